// Round 7
// baseline (356.272 us; speedup 1.0000x reference)
//
#include <hip/hip_runtime.h>

#define NN 50000
#define NE 800000
#define ET (NE + NN)   // 850000 edges incl. self-loops
#define SCAN_B 256
#define NBLK ((NN + SCAN_B - 1) / SCAN_B)   // 196
#define DCAP1 256      // max degree on fast path, layer1
#define DCAP2 512      // max degree on fast path, layer2

typedef unsigned short u16;
typedef unsigned int u32;

__device__ __forceinline__ float lrelu(float a) { return a > 0.f ? a : 0.2f * a; }
// f32 -> bf16 bits, round-to-nearest-even
__device__ __forceinline__ u16 f2bf(float f) {
    u32 b = __float_as_uint(f);
    b += 0x7FFFu + ((b >> 16) & 1u);
    return (u16)(b >> 16);
}
__device__ __forceinline__ float bf2f(u16 u) {
    return __uint_as_float(((u32)u) << 16);
}

// ---- init: zero degrees, d_out = b2 ----
__global__ void k_init(int* __restrict__ deg, const float* __restrict__ b2,
                       float* __restrict__ out) {
    int i = blockIdx.x * blockDim.x + threadIdx.x;
    if (i < NN)  deg[i] = 0;
    if (i < 128) out[i] = b2[i];
}

// ---- CSR build: degree count ----
__global__ void k_deg(const int* __restrict__ ei, int* __restrict__ deg) {
    int e = blockIdx.x * blockDim.x + threadIdx.x;
    if (e >= ET) return;
    int d = (e < NE) ? ei[NE + e] : e - NE;
    atomicAdd(deg + d, 1);
}

// ---- scan stage A ----
__global__ __launch_bounds__(SCAN_B) void k_scan_a(const int* __restrict__ deg,
                                                   int* __restrict__ off,
                                                   int* __restrict__ bsum) {
    __shared__ int sh[SCAN_B];
    int t = threadIdx.x, i = blockIdx.x * SCAN_B + t;
    int v = (i < NN) ? deg[i] : 0;
    sh[t] = v;
    __syncthreads();
#pragma unroll
    for (int s = 1; s < SCAN_B; s <<= 1) {
        int u = (t >= s) ? sh[t - s] : 0;
        __syncthreads();
        sh[t] += u;
        __syncthreads();
    }
    if (i < NN) off[i] = sh[t] - v;
    if (t == SCAN_B - 1) bsum[blockIdx.x] = sh[t];
}

// ---- scan stage B ----
__global__ __launch_bounds__(SCAN_B) void k_scan_b(int* __restrict__ bsum,
                                                   int* __restrict__ off) {
    __shared__ int sh[SCAN_B];
    int t = threadIdx.x;
    int v = (t < NBLK) ? bsum[t] : 0;
    sh[t] = v;
    __syncthreads();
#pragma unroll
    for (int s = 1; s < SCAN_B; s <<= 1) {
        int u = (t >= s) ? sh[t - s] : 0;
        __syncthreads();
        sh[t] += u;
        __syncthreads();
    }
    if (t < NBLK) bsum[t] = sh[t] - v;
    if (t == 0) off[NN] = ET;
}

// ---- scan stage C ----
__global__ __launch_bounds__(SCAN_B) void k_scan_c(int* __restrict__ off,
                                                   const int* __restrict__ bsum,
                                                   int* __restrict__ cur) {
    int i = blockIdx.x * SCAN_B + threadIdx.x;
    if (i >= NN) return;
    int o = off[i] + bsum[blockIdx.x];
    off[i] = o;
    cur[i] = o;
}

// ---- CSR fill ----
__global__ void k_fill(const int* __restrict__ ei, int* __restrict__ cur,
                       int* __restrict__ csr) {
    int e = blockIdx.x * blockDim.x + threadIdx.x;
    if (e >= ET) return;
    int s, d;
    if (e < NE) { s = ei[e]; d = ei[NE + e]; } else { s = d = e - NE; }
    int pos = atomicAdd(cur + d, 1);
    csr[pos] = s;
}

// ---- layer1 node transform: 4 nodes per block ----
__global__ __launch_bounds__(512) void k_node1(
        const float* __restrict__ x, const float* __restrict__ W1,
        const float* __restrict__ as1, const float* __restrict__ ad1,
        u16* __restrict__ hbf, float* __restrict__ asrc, float* __restrict__ adst) {
    int t = threadIdx.x;
    int n = blockIdx.x * 4 + (t >> 7);
    int c = t & 127;
    if (n >= NN) return;
    float x0 = x[2 * n], x1 = x[2 * n + 1];
    float hv = fmaf(x0, W1[c], x1 * W1[128 + c]);
    hbf[(size_t)n * 128 + c] = f2bf(hv);
    float ps = hv * as1[c], pd = hv * ad1[c];
#pragma unroll
    for (int m = 16; m >= 1; m >>= 1) {
        ps += __shfl_xor(ps, m);
        pd += __shfl_xor(pd, m);
    }
    if ((c & 31) == 0) {
        int hd = c >> 5;
        asrc[n * 4 + hd] = ps;
        adst[n * 4 + hd] = pd;
    }
}

// ---- layer1 gather-aggregate: edge-parallel softmax in LDS, heads=4 ----
__global__ __launch_bounds__(128) void k_agg1v(
        const int* __restrict__ off, const int* __restrict__ csr,
        const float* __restrict__ asrc, const float* __restrict__ adst,
        const u16* __restrict__ hbf, float* __restrict__ ob) {
    __shared__ float2 pair[4][DCAP1];      // {ex, src_bits}, [head][edge]
    __shared__ float redm[4], redd[4];
    int n = blockIdx.x, t = threadIdx.x;
    int hd = t >> 5, l = t & 31;
    int e0 = off[n], deg = off[n + 1] - e0;
    float ad = adst[n * 4 + hd];

    if (deg <= DCAP1) {
        float mymax = -1e30f;
        for (int e = l; e < deg; e += 32) {
            int s = csr[e0 + e];
            float al = lrelu(asrc[s * 4 + hd] + ad);
            pair[hd][e] = make_float2(al, __int_as_float(s));
            mymax = fmaxf(mymax, al);
        }
#pragma unroll
        for (int m = 16; m >= 1; m >>= 1) mymax = fmaxf(mymax, __shfl_xor(mymax, m));
        if (l == 0) redm[hd] = mymax;
        __syncthreads();
        float amax = redm[hd];
        float myden = 0.f;
        for (int e = l; e < deg; e += 32) {
            float ex = __expf(pair[hd][e].x - amax);
            pair[hd][e].x = ex;
            myden += ex;
        }
#pragma unroll
        for (int m = 16; m >= 1; m >>= 1) myden += __shfl_xor(myden, m);
        if (l == 0) redd[hd] = myden;
        __syncthreads();
        float inv = 1.f / (redd[hd] + 1e-16f);
        const u16* hc = hbf + t;
        float acc = 0.f;
#pragma unroll 4
        for (int e = 0; e < deg; ++e) {
            float2 p = pair[hd][e];
            acc = fmaf(p.x, bf2f(hc[(size_t)__float_as_int(p.y) * 128]), acc);
        }
        ob[(size_t)n * 128 + t] = acc * inv;
    } else {
        float amax = -1e30f;
        for (int e = e0; e < e0 + deg; ++e) {
            int s = csr[e];
            amax = fmaxf(amax, lrelu(asrc[s * 4 + hd] + ad));
        }
        float den = 0.f, acc = 0.f;
        for (int e = e0; e < e0 + deg; ++e) {
            int s = csr[e];
            float ex = __expf(lrelu(asrc[s * 4 + hd] + ad) - amax);
            den += ex;
            acc = fmaf(ex, bf2f(hbf[(size_t)s * 128 + t]), acc);
        }
        ob[(size_t)n * 128 + t] = acc / (den + 1e-16f);
    }
}

// ---- layer2 node transform GEMM, IN-PLACE over ob, k-block-4 inner loop,
//      double-buffered W2 staging with register prefetch ----
__global__ __launch_bounds__(256) void k_node2t(
        float* ob, const float* __restrict__ b1,
        const float* __restrict__ W2, const float* __restrict__ as2,
        const float* __restrict__ ad2,
        float* __restrict__ asrc, float* __restrict__ adst) {
    __shared__ float Wl[2][32][128];   // 32 KB double buffer
    __shared__ float xt[32][128];      // 16 KB
    int t = threadIdx.x;
    int tc = t & 31, tr = t >> 5;
    int n0 = blockIdx.x * 32;

    // stage xt (fused bias + relu)
#pragma unroll
    for (int i = 0; i < 4; ++i) {
        int f4 = t + i * 256;
        int r = f4 >> 5, c4 = f4 & 31;
        float4 v = make_float4(0.f, 0.f, 0.f, 0.f);
        int n = n0 + r;
        if (n < NN) {
            v = *(const float4*)(ob + (size_t)n * 128 + c4 * 4);
            float4 bb = *(const float4*)(b1 + c4 * 4);
            v.x = fmaxf(v.x + bb.x, 0.f);
            v.y = fmaxf(v.y + bb.y, 0.f);
            v.z = fmaxf(v.z + bb.z, 0.f);
            v.w = fmaxf(v.w + bb.w, 0.f);
        }
        *(float4*)(&xt[r][c4 * 4]) = v;
    }

    float acc[4][4] = {{0.f}};

    // W2 chunk staging helpers (chunk kc = rows kc*32..kc*32+31)
    int sr = t >> 5, sc4 = t & 31;     // this thread's (row, col4) within chunk stride 8 rows
    auto ldchunk = [&](int kc, float4* w) {
#pragma unroll
        for (int i = 0; i < 4; ++i)
            w[i] = *(const float4*)(W2 + (size_t)(kc * 32 + sr + i * 8) * 128 + sc4 * 4);
    };
    auto wrchunk = [&](int buf, const float4* w) {
#pragma unroll
        for (int i = 0; i < 4; ++i)
            *(float4*)(&Wl[buf][sr + i * 8][sc4 * 4]) = w[i];
    };
    auto compute = [&](int buf, int kc) {
#pragma unroll
        for (int k4 = 0; k4 < 32; k4 += 4) {
            float4 xv0 = *(const float4*)(&xt[tr * 4 + 0][kc * 32 + k4]);
            float4 xv1 = *(const float4*)(&xt[tr * 4 + 1][kc * 32 + k4]);
            float4 xv2 = *(const float4*)(&xt[tr * 4 + 2][kc * 32 + k4]);
            float4 xv3 = *(const float4*)(&xt[tr * 4 + 3][kc * 32 + k4]);
#pragma unroll
            for (int kk = 0; kk < 4; ++kk) {
                float4 w = *(const float4*)(&Wl[buf][k4 + kk][tc * 4]);
                float x0 = (kk == 0) ? xv0.x : (kk == 1) ? xv0.y : (kk == 2) ? xv0.z : xv0.w;
                float x1 = (kk == 0) ? xv1.x : (kk == 1) ? xv1.y : (kk == 2) ? xv1.z : xv1.w;
                float x2 = (kk == 0) ? xv2.x : (kk == 1) ? xv2.y : (kk == 2) ? xv2.z : xv2.w;
                float x3 = (kk == 0) ? xv3.x : (kk == 1) ? xv3.y : (kk == 2) ? xv3.z : xv3.w;
                acc[0][0] = fmaf(x0, w.x, acc[0][0]);
                acc[0][1] = fmaf(x0, w.y, acc[0][1]);
                acc[0][2] = fmaf(x0, w.z, acc[0][2]);
                acc[0][3] = fmaf(x0, w.w, acc[0][3]);
                acc[1][0] = fmaf(x1, w.x, acc[1][0]);
                acc[1][1] = fmaf(x1, w.y, acc[1][1]);
                acc[1][2] = fmaf(x1, w.z, acc[1][2]);
                acc[1][3] = fmaf(x1, w.w, acc[1][3]);
                acc[2][0] = fmaf(x2, w.x, acc[2][0]);
                acc[2][1] = fmaf(x2, w.y, acc[2][1]);
                acc[2][2] = fmaf(x2, w.z, acc[2][2]);
                acc[2][3] = fmaf(x2, w.w, acc[2][3]);
                acc[3][0] = fmaf(x3, w.x, acc[3][0]);
                acc[3][1] = fmaf(x3, w.y, acc[3][1]);
                acc[3][2] = fmaf(x3, w.z, acc[3][2]);
                acc[3][3] = fmaf(x3, w.w, acc[3][3]);
            }
        }
    };

    float4 wa[4], wb[4];
    ldchunk(0, wa);
    wrchunk(0, wa);
    ldchunk(1, wb);            // in flight during chunk-0 compute
    __syncthreads();           // xt + Wl[0] ready

    compute(0, 0);
    wrchunk(1, wb);            // waits vmcnt for wb only here
    ldchunk(2, wa);
    __syncthreads();

    compute(1, 1);
    wrchunk(0, wa);
    ldchunk(3, wb);
    __syncthreads();

    compute(0, 2);
    wrchunk(1, wb);
    __syncthreads();

    compute(1, 3);

    // epilogue: store h2 (f32, in place) + fused attention dots
    float4 av = *(const float4*)(as2 + tc * 4);
    float4 dv = *(const float4*)(ad2 + tc * 4);
#pragma unroll
    for (int j = 0; j < 4; ++j) {
        int n = n0 + tr * 4 + j;
        float ps = acc[j][0] * av.x + acc[j][1] * av.y +
                   acc[j][2] * av.z + acc[j][3] * av.w;
        float pd = acc[j][0] * dv.x + acc[j][1] * dv.y +
                   acc[j][2] * dv.z + acc[j][3] * dv.w;
#pragma unroll
        for (int m = 16; m >= 1; m >>= 1) {
            ps += __shfl_xor(ps, m);
            pd += __shfl_xor(pd, m);
        }
        if (n < NN) {
            *(float4*)(ob + (size_t)n * 128 + tc * 4) =
                make_float4(acc[j][0], acc[j][1], acc[j][2], acc[j][3]);
            if (tc == 0) { asrc[n] = ps; adst[n] = pd; }
        }
    }
}

// ---- f32 -> packed bf16 convert (h2 staging for the gather) ----
__global__ __launch_bounds__(256) void k_cvt(const float* __restrict__ in,
                                             u32* __restrict__ out) {
    int i = blockIdx.x * blockDim.x + threadIdx.x;   // pair index
    if (i >= NN * 64) return;
    float2 v = *(const float2*)(in + (size_t)i * 2);
    out[i] = (u32)f2bf(v.x) | ((u32)f2bf(v.y) << 16);
}

// ---- layer2 gather-aggregate: heads=1 ----
__global__ __launch_bounds__(128) void k_agg2v(
        const int* __restrict__ off, const int* __restrict__ csr,
        const float* __restrict__ asrc, const float* __restrict__ adst,
        const u16* __restrict__ hbf, float* __restrict__ ob) {
    __shared__ float2 pair[DCAP2];
    __shared__ float red[4];
    int n = blockIdx.x, t = threadIdx.x;
    int e0 = off[n], deg = off[n + 1] - e0;
    float ad = adst[n];

    if (deg <= DCAP2) {
        float mymax = -1e30f;
        for (int e = t; e < deg; e += 128) {
            int s = csr[e0 + e];
            float al = lrelu(asrc[s] + ad);
            pair[e] = make_float2(al, __int_as_float(s));
            mymax = fmaxf(mymax, al);
        }
#pragma unroll
        for (int m = 32; m >= 1; m >>= 1) mymax = fmaxf(mymax, __shfl_xor(mymax, m));
        if ((t & 63) == 0) red[t >> 6] = mymax;
        __syncthreads();
        float amax = fmaxf(red[0], red[1]);
        float myden = 0.f;
        for (int e = t; e < deg; e += 128) {
            float ex = __expf(pair[e].x - amax);
            pair[e].x = ex;
            myden += ex;
        }
#pragma unroll
        for (int m = 32; m >= 1; m >>= 1) myden += __shfl_xor(myden, m);
        if ((t & 63) == 0) red[2 + (t >> 6)] = myden;
        __syncthreads();
        float inv = 1.f / (red[2] + red[3] + 1e-16f);
        const u16* hc = hbf + t;
        float acc = 0.f;
#pragma unroll 4
        for (int e = 0; e < deg; ++e) {
            float2 p = pair[e];
            acc = fmaf(p.x, bf2f(hc[(size_t)__float_as_int(p.y) * 128]), acc);
        }
        ob[(size_t)n * 128 + t] = acc * inv;
    } else {
        float amax = -1e30f;
        for (int e = e0; e < e0 + deg; ++e) {
            int s = csr[e];
            amax = fmaxf(amax, lrelu(asrc[s] + ad));
        }
        float den = 0.f, acc = 0.f;
        for (int e = e0; e < e0 + deg; ++e) {
            int s = csr[e];
            float ex = __expf(lrelu(asrc[s] + ad) - amax);
            den += ex;
            acc = fmaf(ex, bf2f(hbf[(size_t)s * 128 + t]), acc);
        }
        ob[(size_t)n * 128 + t] = acc / (den + 1e-16f);
    }
}

// ---- final: mean over nodes, d_out pre-set to b2 ----
__global__ __launch_bounds__(128) void k_final(const float* __restrict__ ob,
                                               float* __restrict__ out) {
    int c = threadIdx.x;
    float acc = 0.f;
    for (int n = blockIdx.x; n < NN; n += gridDim.x) acc += ob[n * 128 + c];
    atomicAdd(out + c, acc * (1.0f / NN));
}

extern "C" void kernel_launch(void* const* d_in, const int* in_sizes, int n_in,
                              void* d_out, int out_size, void* d_ws, size_t ws_size,
                              hipStream_t stream) {
    const float* x   = (const float*)d_in[0];
    const int*   ei  = (const int*)d_in[1];
    const float* W1  = (const float*)d_in[2];
    const float* as1 = (const float*)d_in[3];
    const float* ad1 = (const float*)d_in[4];
    const float* b1  = (const float*)d_in[5];
    const float* W2  = (const float*)d_in[6];
    const float* as2 = (const float*)d_in[7];
    const float* ad2 = (const float*)d_in[8];
    const float* b2  = (const float*)d_in[9];
    float* out = (float*)d_out;

    char* ws   = (char*)d_ws;
    u16*  hbf  = (u16*)ws;                               // NN*128 bf16 (h1, then h2)
    float* ob  = (float*)(ws + (size_t)NN * 128 * 2);    // NN*128 f32 (out1/h2f/out2)
    float* asr1 = ob + (size_t)NN * 128;                 // NN*4
    float* adt1 = asr1 + NN * 4;                         // NN*4
    float* asr2 = adt1 + NN * 4;                         // NN
    float* adt2 = asr2 + NN;                             // NN
    int* deg    = (int*)(adt2 + NN);                     // NN
    int* off    = deg + NN;                              // NN+1
    int* cur    = off + NN + 1;                          // NN
    int* bsum   = cur + NN;                              // NBLK
    int* csr    = bsum + NBLK;                           // ET

    // CSR build (shared by both layers)
    k_init<<<(NN + 255) / 256, 256, 0, stream>>>(deg, b2, out);
    k_deg<<<(ET + 255) / 256, 256, 0, stream>>>(ei, deg);
    k_scan_a<<<NBLK, SCAN_B, 0, stream>>>(deg, off, bsum);
    k_scan_b<<<1, SCAN_B, 0, stream>>>(bsum, off);
    k_scan_c<<<NBLK, SCAN_B, 0, stream>>>(off, bsum, cur);
    k_fill<<<(ET + 255) / 256, 256, 0, stream>>>(ei, cur, csr);

    // layer 1
    k_node1<<<(NN + 3) / 4, 512, 0, stream>>>(x, W1, as1, ad1, hbf, asr1, adt1);
    k_agg1v<<<NN, 128, 0, stream>>>(off, csr, asr1, adt1, hbf, ob);

    // layer 2: GEMM in-place on ob, then convert to bf16 into hbf
    k_node2t<<<(NN + 31) / 32, 256, 0, stream>>>(ob, b1, W2, as2, ad2, asr2, adt2);
    k_cvt<<<(NN * 64 + 255) / 256, 256, 0, stream>>>(ob, (u32*)hbf);
    k_agg2v<<<NN, 128, 0, stream>>>(off, csr, asr2, adt2, hbf, ob);

    // mean pool (+b2 already in out)
    k_final<<<256, 128, 0, stream>>>(ob, out);
}

// Round 9
// 294.516 us; speedup vs baseline: 1.2097x; 1.2097x over previous
//
#include <hip/hip_runtime.h>

#define NN 50000
#define NE 800000
#define ET (NE + NN)   // 850000 edges incl. self-loops
#define SCAN_B 256
#define NBLK ((NN + SCAN_B - 1) / SCAN_B)   // 196
#define DCAP1 256      // max degree on fast path, layer1
#define DCAP2 512      // max degree on fast path, layer2

typedef unsigned short u16;
typedef unsigned int u32;
typedef __attribute__((ext_vector_type(8))) short bf16x8;
typedef __attribute__((ext_vector_type(4))) float f32x4;

__device__ __forceinline__ float lrelu(float a) { return a > 0.f ? a : 0.2f * a; }
// f32 -> bf16 bits, round-to-nearest-even
__device__ __forceinline__ u16 f2bf(float f) {
    u32 b = __float_as_uint(f);
    b += 0x7FFFu + ((b >> 16) & 1u);
    return (u16)(b >> 16);
}
__device__ __forceinline__ float bf2f(u16 u) {
    return __uint_as_float(((u32)u) << 16);
}

// ---- init: zero degrees, d_out = b2, W2 -> bf16 transposed [col][k] ----
__global__ void k_init(int* __restrict__ deg, const float* __restrict__ b2,
                       float* __restrict__ out, const float* __restrict__ W2,
                       u16* __restrict__ w2t) {
    int i = blockIdx.x * blockDim.x + threadIdx.x;
    if (i < NN)  deg[i] = 0;
    if (i < 128) out[i] = b2[i];
    if (i < 128 * 128) {
        int k = i >> 7, c = i & 127;
        w2t[c * 128 + k] = f2bf(W2[i]);
    }
}

// ---- CSR build: degree count ----
__global__ void k_deg(const int* __restrict__ ei, int* __restrict__ deg) {
    int e = blockIdx.x * blockDim.x + threadIdx.x;
    if (e >= ET) return;
    int d = (e < NE) ? ei[NE + e] : e - NE;
    atomicAdd(deg + d, 1);
}

// ---- scan stage A ----
__global__ __launch_bounds__(SCAN_B) void k_scan_a(const int* __restrict__ deg,
                                                   int* __restrict__ off,
                                                   int* __restrict__ bsum) {
    __shared__ int sh[SCAN_B];
    int t = threadIdx.x, i = blockIdx.x * SCAN_B + t;
    int v = (i < NN) ? deg[i] : 0;
    sh[t] = v;
    __syncthreads();
#pragma unroll
    for (int s = 1; s < SCAN_B; s <<= 1) {
        int u = (t >= s) ? sh[t - s] : 0;
        __syncthreads();
        sh[t] += u;
        __syncthreads();
    }
    if (i < NN) off[i] = sh[t] - v;
    if (t == SCAN_B - 1) bsum[blockIdx.x] = sh[t];
}

// ---- scan stage B ----
__global__ __launch_bounds__(SCAN_B) void k_scan_b(int* __restrict__ bsum,
                                                   int* __restrict__ off) {
    __shared__ int sh[SCAN_B];
    int t = threadIdx.x;
    int v = (t < NBLK) ? bsum[t] : 0;
    sh[t] = v;
    __syncthreads();
#pragma unroll
    for (int s = 1; s < SCAN_B; s <<= 1) {
        int u = (t >= s) ? sh[t - s] : 0;
        __syncthreads();
        sh[t] += u;
        __syncthreads();
    }
    if (t < NBLK) bsum[t] = sh[t] - v;
    if (t == 0) off[NN] = ET;
}

// ---- scan stage C ----
__global__ __launch_bounds__(SCAN_B) void k_scan_c(int* __restrict__ off,
                                                   const int* __restrict__ bsum,
                                                   int* __restrict__ cur) {
    int i = blockIdx.x * SCAN_B + threadIdx.x;
    if (i >= NN) return;
    int o = off[i] + bsum[blockIdx.x];
    off[i] = o;
    cur[i] = o;
}

// ---- CSR fill ----
__global__ void k_fill(const int* __restrict__ ei, int* __restrict__ cur,
                       int* __restrict__ csr) {
    int e = blockIdx.x * blockDim.x + threadIdx.x;
    if (e >= ET) return;
    int s, d;
    if (e < NE) { s = ei[e]; d = ei[NE + e]; } else { s = d = e - NE; }
    int pos = atomicAdd(cur + d, 1);
    csr[pos] = s;
}

// ---- layer1 node transform: 4 nodes per block ----
__global__ __launch_bounds__(512) void k_node1(
        const float* __restrict__ x, const float* __restrict__ W1,
        const float* __restrict__ as1, const float* __restrict__ ad1,
        u16* __restrict__ hbf, float* __restrict__ asrc, float* __restrict__ adst) {
    int t = threadIdx.x;
    int n = blockIdx.x * 4 + (t >> 7);
    int c = t & 127;
    if (n >= NN) return;
    float x0 = x[2 * n], x1 = x[2 * n + 1];
    float hv = fmaf(x0, W1[c], x1 * W1[128 + c]);
    hbf[(size_t)n * 128 + c] = f2bf(hv);
    float ps = hv * as1[c], pd = hv * ad1[c];
#pragma unroll
    for (int m = 16; m >= 1; m >>= 1) {
        ps += __shfl_xor(ps, m);
        pd += __shfl_xor(pd, m);
    }
    if ((c & 31) == 0) {
        int hd = c >> 5;
        asrc[n * 4 + hd] = ps;
        adst[n * 4 + hd] = pd;
    }
}

// ---- layer1 gather-aggregate: edge-parallel softmax in LDS, heads=4 ----
__global__ __launch_bounds__(128) void k_agg1v(
        const int* __restrict__ off, const int* __restrict__ csr,
        const float* __restrict__ asrc, const float* __restrict__ adst,
        const u16* __restrict__ hbf, float* __restrict__ ob) {
    __shared__ float2 pair[4][DCAP1];      // {ex, src_bits}, [head][edge]
    __shared__ float redm[4], redd[4];
    int n = blockIdx.x, t = threadIdx.x;
    int hd = t >> 5, l = t & 31;
    int e0 = off[n], deg = off[n + 1] - e0;
    float ad = adst[n * 4 + hd];

    if (deg <= DCAP1) {
        float mymax = -1e30f;
        for (int e = l; e < deg; e += 32) {
            int s = csr[e0 + e];
            float al = lrelu(asrc[s * 4 + hd] + ad);
            pair[hd][e] = make_float2(al, __int_as_float(s));
            mymax = fmaxf(mymax, al);
        }
#pragma unroll
        for (int m = 16; m >= 1; m >>= 1) mymax = fmaxf(mymax, __shfl_xor(mymax, m));
        if (l == 0) redm[hd] = mymax;
        __syncthreads();
        float amax = redm[hd];
        float myden = 0.f;
        for (int e = l; e < deg; e += 32) {
            float ex = __expf(pair[hd][e].x - amax);
            pair[hd][e].x = ex;
            myden += ex;
        }
#pragma unroll
        for (int m = 16; m >= 1; m >>= 1) myden += __shfl_xor(myden, m);
        if (l == 0) redd[hd] = myden;
        __syncthreads();
        float inv = 1.f / (redd[hd] + 1e-16f);
        const u16* hc = hbf + t;
        float acc = 0.f;
#pragma unroll 4
        for (int e = 0; e < deg; ++e) {
            float2 p = pair[hd][e];
            acc = fmaf(p.x, bf2f(hc[(size_t)__float_as_int(p.y) * 128]), acc);
        }
        ob[(size_t)n * 128 + t] = acc * inv;
    } else {
        float amax = -1e30f;
        for (int e = e0; e < e0 + deg; ++e) {
            int s = csr[e];
            amax = fmaxf(amax, lrelu(asrc[s * 4 + hd] + ad));
        }
        float den = 0.f, acc = 0.f;
        for (int e = e0; e < e0 + deg; ++e) {
            int s = csr[e];
            float ex = __expf(lrelu(asrc[s * 4 + hd] + ad) - amax);
            den += ex;
            acc = fmaf(ex, bf2f(hbf[(size_t)s * 128 + t]), acc);
        }
        ob[(size_t)n * 128 + t] = acc / (den + 1e-16f);
    }
}

// ---- layer2 node transform via MFMA bf16:
//      x2 = relu(ob+b1) -> bf16; h2 = x2@W2 (bf16 inputs, f32 accum);
//      writes h2 as bf16 (hbf) + fused attention dots.
//      block 256 thr / 4 waves; tile 64 rows x 128 cols; K=128 in LDS.
//      LDS XOR-swizzle: byte ^= (row&7)<<4 (conflict-floor ds_read_b128).
__global__ __launch_bounds__(256) void k_node2m(
        const float* __restrict__ ob, const float* __restrict__ b1,
        const u16* __restrict__ w2t, const float* __restrict__ as2,
        const float* __restrict__ ad2, u16* __restrict__ h2bf,
        float* __restrict__ asrc, float* __restrict__ adst) {
    __shared__ u16 xt[64 * 128];    // 16 KB, x-tile bf16, swizzled rows
    __shared__ u16 wt[128 * 128];   // 32 KB, W2T [col][k] bf16, swizzled rows
    int t = threadIdx.x;
    int n0 = blockIdx.x * 64;

    // stage x-tile: fused bias+relu, f32 -> bf16, swizzled b64 writes
#pragma unroll
    for (int i = 0; i < 8; ++i) {
        int f4 = t + i * 256;                  // 0..2047 float4 slots
        int r = f4 >> 5, c4 = f4 & 31;
        int n = n0 + r;
        float4 v = make_float4(0.f, 0.f, 0.f, 0.f);
        if (n < NN) {
            v = *(const float4*)(ob + (size_t)n * 128 + c4 * 4);
            float4 bb = *(const float4*)(b1 + c4 * 4);
            v.x = fmaxf(v.x + bb.x, 0.f);
            v.y = fmaxf(v.y + bb.y, 0.f);
            v.z = fmaxf(v.z + bb.z, 0.f);
            v.w = fmaxf(v.w + bb.w, 0.f);
        }
        u32 p0 = (u32)f2bf(v.x) | ((u32)f2bf(v.y) << 16);
        u32 p1 = (u32)f2bf(v.z) | ((u32)f2bf(v.w) << 16);
        int offb = r * 256 + ((c4 * 8) ^ ((r & 7) << 4));
        *(uint2*)((char*)xt + offb) = make_uint2(p0, p1);
    }
    // stage W2T tile: straight bf16 copy, swizzled b128 writes
    // wt geometry: 128 rows (output col) x 256 B (128 k-values) = 16 chunks/row
#pragma unroll
    for (int i = 0; i < 8; ++i) {
        int c8 = t + i * 256;                  // 0..2047 16B chunks
        int row = c8 >> 4, k8 = c8 & 15;       // FIX: 16 chunks per row
        uint4 wv = *(const uint4*)(w2t + row * 128 + k8 * 8);
        int offb = row * 256 + ((k8 * 16) ^ ((row & 7) << 4));
        *(uint4*)((char*)wt + offb) = wv;
    }
    __syncthreads();

    int l = t & 63, w = t >> 6;
    int lr = l & 15, lg = l >> 4;              // lane row-in-tile, k-group

    // A fragments: row = w*16 + lr, k = kc*32 + lg*8 + j  (contiguous 16B)
    bf16x8 afr[4];
    int ar = w * 16 + lr;
#pragma unroll
    for (int kc = 0; kc < 4; ++kc) {
        int kbyte = kc * 64 + lg * 16;
        afr[kc] = *(const bf16x8*)((char*)xt + ar * 256 + (kbyte ^ ((ar & 7) << 4)));
    }

    f32x4 acc[8];
#pragma unroll
    for (int ct = 0; ct < 8; ++ct) {
        f32x4 c = {0.f, 0.f, 0.f, 0.f};
        int br = ct * 16 + lr;                 // B: col = ct*16+lr, k contiguous
#pragma unroll
        for (int kc = 0; kc < 4; ++kc) {
            int kbyte = kc * 64 + lg * 16;
            bf16x8 b = *(const bf16x8*)((char*)wt + br * 256 + (kbyte ^ ((br & 7) << 4)));
            c = __builtin_amdgcn_mfma_f32_16x16x32_bf16(afr[kc], b, c, 0, 0, 0);
        }
        acc[ct] = c;
    }

    // epilogue: C/D layout col = lr, row = lg*4 + reg  [m89]
    float asv[8], adv[8];
#pragma unroll
    for (int ct = 0; ct < 8; ++ct) {
        asv[ct] = as2[ct * 16 + lr];
        adv[ct] = ad2[ct * 16 + lr];
    }
#pragma unroll
    for (int reg = 0; reg < 4; ++reg) {
        float ps = 0.f, pd = 0.f;
#pragma unroll
        for (int ct = 0; ct < 8; ++ct) {
            ps = fmaf(acc[ct][reg], asv[ct], ps);
            pd = fmaf(acc[ct][reg], adv[ct], pd);
        }
#pragma unroll
        for (int m = 8; m >= 1; m >>= 1) {     // reduce over lr (16 lanes)
            ps += __shfl_xor(ps, m);
            pd += __shfl_xor(pd, m);
        }
        int n = n0 + w * 16 + lg * 4 + reg;
        if (n < NN) {
#pragma unroll
            for (int ct = 0; ct < 8; ++ct)
                h2bf[(size_t)n * 128 + ct * 16 + lr] = f2bf(acc[ct][reg]);
            if (lr == 0) { asrc[n] = ps; adst[n] = pd; }
        }
    }
}

// ---- layer2 gather-aggregate: heads=1 ----
__global__ __launch_bounds__(128) void k_agg2v(
        const int* __restrict__ off, const int* __restrict__ csr,
        const float* __restrict__ asrc, const float* __restrict__ adst,
        const u16* __restrict__ hbf, float* __restrict__ ob) {
    __shared__ float2 pair[DCAP2];
    __shared__ float red[4];
    int n = blockIdx.x, t = threadIdx.x;
    int e0 = off[n], deg = off[n + 1] - e0;
    float ad = adst[n];

    if (deg <= DCAP2) {
        float mymax = -1e30f;
        for (int e = t; e < deg; e += 128) {
            int s = csr[e0 + e];
            float al = lrelu(asrc[s] + ad);
            pair[e] = make_float2(al, __int_as_float(s));
            mymax = fmaxf(mymax, al);
        }
#pragma unroll
        for (int m = 32; m >= 1; m >>= 1) mymax = fmaxf(mymax, __shfl_xor(mymax, m));
        if ((t & 63) == 0) red[t >> 6] = mymax;
        __syncthreads();
        float amax = fmaxf(red[0], red[1]);
        float myden = 0.f;
        for (int e = t; e < deg; e += 128) {
            float ex = __expf(pair[e].x - amax);
            pair[e].x = ex;
            myden += ex;
        }
#pragma unroll
        for (int m = 32; m >= 1; m >>= 1) myden += __shfl_xor(myden, m);
        if ((t & 63) == 0) red[2 + (t >> 6)] = myden;
        __syncthreads();
        float inv = 1.f / (red[2] + red[3] + 1e-16f);
        const u16* hc = hbf + t;
        float acc = 0.f;
#pragma unroll 4
        for (int e = 0; e < deg; ++e) {
            float2 p = pair[e];
            acc = fmaf(p.x, bf2f(hc[(size_t)__float_as_int(p.y) * 128]), acc);
        }
        ob[(size_t)n * 128 + t] = acc * inv;
    } else {
        float amax = -1e30f;
        for (int e = e0; e < e0 + deg; ++e) {
            int s = csr[e];
            amax = fmaxf(amax, lrelu(asrc[s] + ad));
        }
        float den = 0.f, acc = 0.f;
        for (int e = e0; e < e0 + deg; ++e) {
            int s = csr[e];
            float ex = __expf(lrelu(asrc[s] + ad) - amax);
            den += ex;
            acc = fmaf(ex, bf2f(hbf[(size_t)s * 128 + t]), acc);
        }
        ob[(size_t)n * 128 + t] = acc / (den + 1e-16f);
    }
}

// ---- final: mean over nodes, d_out pre-set to b2 ----
__global__ __launch_bounds__(128) void k_final(const float* __restrict__ ob,
                                               float* __restrict__ out) {
    int c = threadIdx.x;
    float acc = 0.f;
    for (int n = blockIdx.x; n < NN; n += gridDim.x) acc += ob[n * 128 + c];
    atomicAdd(out + c, acc * (1.0f / NN));
}

extern "C" void kernel_launch(void* const* d_in, const int* in_sizes, int n_in,
                              void* d_out, int out_size, void* d_ws, size_t ws_size,
                              hipStream_t stream) {
    const float* x   = (const float*)d_in[0];
    const int*   ei  = (const int*)d_in[1];
    const float* W1  = (const float*)d_in[2];
    const float* as1 = (const float*)d_in[3];
    const float* ad1 = (const float*)d_in[4];
    const float* b1  = (const float*)d_in[5];
    const float* W2  = (const float*)d_in[6];
    const float* as2 = (const float*)d_in[7];
    const float* ad2 = (const float*)d_in[8];
    const float* b2  = (const float*)d_in[9];
    float* out = (float*)d_out;

    char* ws   = (char*)d_ws;
    u16*  hbf  = (u16*)ws;                               // NN*128 bf16 (h1, then h2)
    float* ob  = (float*)(ws + (size_t)NN * 128 * 2);    // NN*128 f32 (out1, then out2)
    float* asr1 = ob + (size_t)NN * 128;                 // NN*4
    float* adt1 = asr1 + NN * 4;                         // NN*4
    float* asr2 = adt1 + NN * 4;                         // NN
    float* adt2 = asr2 + NN;                             // NN
    int* deg    = (int*)(adt2 + NN);                     // NN
    int* off    = deg + NN;                              // NN+1
    int* cur    = off + NN + 1;                          // NN
    int* bsum   = cur + NN;                              // NBLK
    int* csr    = bsum + NBLK;                           // ET
    u16* w2t    = (u16*)(csr + ET);                      // 128*128 bf16

    // CSR build (shared by both layers) + W2 bf16 transpose
    k_init<<<(NN + 255) / 256, 256, 0, stream>>>(deg, b2, out, W2, w2t);
    k_deg<<<(ET + 255) / 256, 256, 0, stream>>>(ei, deg);
    k_scan_a<<<NBLK, SCAN_B, 0, stream>>>(deg, off, bsum);
    k_scan_b<<<1, SCAN_B, 0, stream>>>(bsum, off);
    k_scan_c<<<NBLK, SCAN_B, 0, stream>>>(off, bsum, cur);
    k_fill<<<(ET + 255) / 256, 256, 0, stream>>>(ei, cur, csr);

    // layer 1
    k_node1<<<(NN + 3) / 4, 512, 0, stream>>>(x, W1, as1, ad1, hbf, asr1, adt1);
    k_agg1v<<<NN, 128, 0, stream>>>(off, csr, asr1, adt1, hbf, ob);

    // layer 2: MFMA GEMM reads ob(out1), writes hbf(h2 bf16) + attn dots
    k_node2m<<<(NN + 63) / 64, 256, 0, stream>>>(ob, b1, w2t, as2, ad2, hbf, asr2, adt2);
    k_agg2v<<<NN, 128, 0, stream>>>(off, csr, asr2, adt2, hbf, ob);

    // mean pool (+b2 already in out)
    k_final<<<256, 128, 0, stream>>>(ob, out);
}

// Round 10
// 266.825 us; speedup vs baseline: 1.3352x; 1.1038x over previous
//
#include <hip/hip_runtime.h>

#define NN 50000
#define NE 800000
#define ET (NE + NN)   // 850000 edges incl. self-loops
#define SCAN_B 256
#define NBLK ((NN + SCAN_B - 1) / SCAN_B)   // 196
#define DCAP 128       // max degree on fast path (Poisson(16)+1: max ~50)

typedef unsigned short u16;
typedef unsigned int u32;
typedef __attribute__((ext_vector_type(8))) short bf16x8;
typedef __attribute__((ext_vector_type(4))) float f32x4;

__device__ __forceinline__ float lrelu(float a) { return a > 0.f ? a : 0.2f * a; }
// f32 -> bf16 bits, round-to-nearest-even
__device__ __forceinline__ u16 f2bf(float f) {
    u32 b = __float_as_uint(f);
    b += 0x7FFFu + ((b >> 16) & 1u);
    return (u16)(b >> 16);
}
__device__ __forceinline__ float bf2f(u16 u) {
    return __uint_as_float(((u32)u) << 16);
}

// ---- init: zero degrees, d_out = b2, W2 -> bf16 transposed [col][k] ----
__global__ void k_init(int* __restrict__ deg, const float* __restrict__ b2,
                       float* __restrict__ out, const float* __restrict__ W2,
                       u16* __restrict__ w2t) {
    int i = blockIdx.x * blockDim.x + threadIdx.x;
    if (i < NN)  deg[i] = 0;
    if (i < 128) out[i] = b2[i];
    if (i < 128 * 128) {
        int k = i >> 7, c = i & 127;
        w2t[c * 128 + k] = f2bf(W2[i]);
    }
}

// ---- CSR build: degree count ----
__global__ void k_deg(const int* __restrict__ ei, int* __restrict__ deg) {
    int e = blockIdx.x * blockDim.x + threadIdx.x;
    if (e >= ET) return;
    int d = (e < NE) ? ei[NE + e] : e - NE;
    atomicAdd(deg + d, 1);
}

// ---- scan stage A ----
__global__ __launch_bounds__(SCAN_B) void k_scan_a(const int* __restrict__ deg,
                                                   int* __restrict__ off,
                                                   int* __restrict__ bsum) {
    __shared__ int sh[SCAN_B];
    int t = threadIdx.x, i = blockIdx.x * SCAN_B + t;
    int v = (i < NN) ? deg[i] : 0;
    sh[t] = v;
    __syncthreads();
#pragma unroll
    for (int s = 1; s < SCAN_B; s <<= 1) {
        int u = (t >= s) ? sh[t - s] : 0;
        __syncthreads();
        sh[t] += u;
        __syncthreads();
    }
    if (i < NN) off[i] = sh[t] - v;
    if (t == SCAN_B - 1) bsum[blockIdx.x] = sh[t];
}

// ---- scan stage B ----
__global__ __launch_bounds__(SCAN_B) void k_scan_b(int* __restrict__ bsum,
                                                   int* __restrict__ off) {
    __shared__ int sh[SCAN_B];
    int t = threadIdx.x;
    int v = (t < NBLK) ? bsum[t] : 0;
    sh[t] = v;
    __syncthreads();
#pragma unroll
    for (int s = 1; s < SCAN_B; s <<= 1) {
        int u = (t >= s) ? sh[t - s] : 0;
        __syncthreads();
        sh[t] += u;
        __syncthreads();
    }
    if (t < NBLK) bsum[t] = sh[t] - v;
    if (t == 0) off[NN] = ET;
}

// ---- scan stage C ----
__global__ __launch_bounds__(SCAN_B) void k_scan_c(int* __restrict__ off,
                                                   const int* __restrict__ bsum,
                                                   int* __restrict__ cur) {
    int i = blockIdx.x * SCAN_B + threadIdx.x;
    if (i >= NN) return;
    int o = off[i] + bsum[blockIdx.x];
    off[i] = o;
    cur[i] = o;
}

// ---- CSR fill ----
__global__ void k_fill(const int* __restrict__ ei, int* __restrict__ cur,
                       int* __restrict__ csr) {
    int e = blockIdx.x * blockDim.x + threadIdx.x;
    if (e >= ET) return;
    int s, d;
    if (e < NE) { s = ei[e]; d = ei[NE + e]; } else { s = d = e - NE; }
    int pos = atomicAdd(cur + d, 1);
    csr[pos] = s;
}

// ---- layer1 node transform: 4 nodes per block ----
__global__ __launch_bounds__(512) void k_node1(
        const float* __restrict__ x, const float* __restrict__ W1,
        const float* __restrict__ as1, const float* __restrict__ ad1,
        u16* __restrict__ hbf, float* __restrict__ asrc, float* __restrict__ adst) {
    int t = threadIdx.x;
    int n = blockIdx.x * 4 + (t >> 7);
    int c = t & 127;
    if (n >= NN) return;
    float x0 = x[2 * n], x1 = x[2 * n + 1];
    float hv = fmaf(x0, W1[c], x1 * W1[128 + c]);
    hbf[(size_t)n * 128 + c] = f2bf(hv);
    float ps = hv * as1[c], pd = hv * ad1[c];
#pragma unroll
    for (int m = 16; m >= 1; m >>= 1) {
        ps += __shfl_xor(ps, m);
        pd += __shfl_xor(pd, m);
    }
    if ((c & 31) == 0) {
        int hd = c >> 5;
        asrc[n * 4 + hd] = ps;
        adst[n * 4 + hd] = pd;
    }
}

// ---- layer1 gather-aggregate: one wave per node, 2 nodes/block, heads=4.
//      No barriers (waves independent; in-wave LDS ops are in program order).
//      Phase B: 2 packed bf16 channels per thread via one u32 load.
//      Epilogue fuses relu(out1+b1) -> packed bf16 x2 for the MFMA GEMM. ----
__global__ __launch_bounds__(128) void k_agg1w(
        const int* __restrict__ off, const int* __restrict__ csr,
        const float* __restrict__ asrc, const float* __restrict__ adst,
        const u16* __restrict__ hbf, const float* __restrict__ b1,
        u32* __restrict__ x2bf) {
    __shared__ float2 pair[2][4][DCAP];    // [wave][head][edge] {ex, bytes(src<<8)}
    int t = threadIdx.x;
    int wv = t >> 6, l = t & 63;
    int n = blockIdx.x * 2 + wv;
    if (n >= NN) return;                   // whole wave exits; no barriers anywhere
    int hd = l >> 4, li = l & 15;          // head, lane-in-head
    int e0 = off[n], deg = off[n + 1] - e0;
    float ad = adst[n * 4 + hd];
    float a0 = 0.f, a1 = 0.f, inv;
    const char* hc = (const char*)hbf + 4 * l;   // this thread's 2-channel base

    if (deg <= DCAP) {
        float mymax = -1e30f;
        for (int e = li; e < deg; e += 16) {
            int s = csr[e0 + e];
            float al = lrelu(asrc[s * 4 + hd] + ad);
            pair[wv][hd][e] = make_float2(al, __int_as_float(s << 8));
            mymax = fmaxf(mymax, al);
        }
#pragma unroll
        for (int m = 8; m >= 1; m >>= 1) mymax = fmaxf(mymax, __shfl_xor(mymax, m));
        float myden = 0.f;
        for (int e = li; e < deg; e += 16) {
            float ex = __expf(pair[wv][hd][e].x - mymax);
            pair[wv][hd][e].x = ex;
            myden += ex;
        }
#pragma unroll
        for (int m = 8; m >= 1; m >>= 1) myden += __shfl_xor(myden, m);
        inv = 1.f / (myden + 1e-16f);
#pragma unroll 4
        for (int e = 0; e < deg; ++e) {
            float2 p = pair[wv][hd][e];
            u32 hw = *(const u32*)(hc + (size_t)(u32)__float_as_int(p.y));
            a0 = fmaf(p.x, __uint_as_float(hw << 16), a0);
            a1 = fmaf(p.x, __uint_as_float(hw & 0xFFFF0000u), a1);
        }
    } else {
        // fallback (never for Poisson(16); correctness guarantee)
        float amax = -1e30f;
        for (int e = e0; e < e0 + deg; ++e)
            amax = fmaxf(amax, lrelu(asrc[csr[e] * 4 + hd] + ad));
        float den = 0.f;
        for (int e = e0; e < e0 + deg; ++e) {
            int s = csr[e];
            float ex = __expf(lrelu(asrc[s * 4 + hd] + ad) - amax);
            den += ex;
            u32 hw = *(const u32*)(hc + (size_t)((u32)s << 8));
            a0 = fmaf(ex, __uint_as_float(hw << 16), a0);
            a1 = fmaf(ex, __uint_as_float(hw & 0xFFFF0000u), a1);
        }
        inv = 1.f / (den + 1e-16f);
    }
    float2 bb = *(const float2*)(b1 + 2 * l);
    float v0 = fmaxf(fmaf(a0, inv, bb.x), 0.f);
    float v1 = fmaxf(fmaf(a1, inv, bb.y), 0.f);
    x2bf[(size_t)n * 64 + l] = (u32)f2bf(v0) | ((u32)f2bf(v1) << 16);
}

// ---- layer2 node transform via MFMA bf16:
//      h2 = x2@W2 (x2 already bf16-packed from agg1w); h2 out bf16 + attn dots.
//      block 256 thr / 4 waves; tile 64 rows x 128 cols; K=128 in LDS.
//      LDS XOR-swizzle: byte ^= (row&7)<<4. ----
__global__ __launch_bounds__(256) void k_node2m(
        const u32* __restrict__ x2bf,
        const u16* __restrict__ w2t, const float* __restrict__ as2,
        const float* __restrict__ ad2, u16* __restrict__ h2bf,
        float* __restrict__ asrc, float* __restrict__ adst) {
    __shared__ u16 xt[64 * 128];    // 16 KB, x-tile bf16, swizzled rows
    __shared__ u16 wt[128 * 128];   // 32 KB, W2T [col][k] bf16, swizzled rows
    int t = threadIdx.x;
    int n0 = blockIdx.x * 64;

    // stage x-tile: pure swizzled copy (bias/relu/bf16 already applied)
    // xt geometry: 64 rows x 256 B = 1024 16B chunks
#pragma unroll
    for (int i = 0; i < 4; ++i) {
        int c8 = t + i * 256;
        int r = c8 >> 4, k8 = c8 & 15;
        int n = n0 + r;
        uint4 v = make_uint4(0, 0, 0, 0);
        if (n < NN) v = *(const uint4*)(x2bf + (size_t)n * 64 + k8 * 4);
        int offb = r * 256 + ((k8 * 16) ^ ((r & 7) << 4));
        *(uint4*)((char*)xt + offb) = v;
    }
    // stage W2T tile: 128 rows x 256 B = 2048 16B chunks
#pragma unroll
    for (int i = 0; i < 8; ++i) {
        int c8 = t + i * 256;
        int row = c8 >> 4, k8 = c8 & 15;
        uint4 wv = *(const uint4*)(w2t + row * 128 + k8 * 8);
        int offb = row * 256 + ((k8 * 16) ^ ((row & 7) << 4));
        *(uint4*)((char*)wt + offb) = wv;
    }
    __syncthreads();

    int l = t & 63, w = t >> 6;
    int lr = l & 15, lg = l >> 4;              // lane row-in-tile, k-group

    // A fragments: row = w*16 + lr, k = kc*32 + lg*8 + j  (contiguous 16B)
    bf16x8 afr[4];
    int ar = w * 16 + lr;
#pragma unroll
    for (int kc = 0; kc < 4; ++kc) {
        int kbyte = kc * 64 + lg * 16;
        afr[kc] = *(const bf16x8*)((char*)xt + ar * 256 + (kbyte ^ ((ar & 7) << 4)));
    }

    f32x4 acc[8];
#pragma unroll
    for (int ct = 0; ct < 8; ++ct) {
        f32x4 c = {0.f, 0.f, 0.f, 0.f};
        int br = ct * 16 + lr;                 // B: col = ct*16+lr, k contiguous
#pragma unroll
        for (int kc = 0; kc < 4; ++kc) {
            int kbyte = kc * 64 + lg * 16;
            bf16x8 b = *(const bf16x8*)((char*)wt + br * 256 + (kbyte ^ ((br & 7) << 4)));
            c = __builtin_amdgcn_mfma_f32_16x16x32_bf16(afr[kc], b, c, 0, 0, 0);
        }
        acc[ct] = c;
    }

    // epilogue: C/D layout col = lr, row = lg*4 + reg  [m89]
    float asv[8], adv[8];
#pragma unroll
    for (int ct = 0; ct < 8; ++ct) {
        asv[ct] = as2[ct * 16 + lr];
        adv[ct] = ad2[ct * 16 + lr];
    }
#pragma unroll
    for (int reg = 0; reg < 4; ++reg) {
        float ps = 0.f, pd = 0.f;
#pragma unroll
        for (int ct = 0; ct < 8; ++ct) {
            ps = fmaf(acc[ct][reg], asv[ct], ps);
            pd = fmaf(acc[ct][reg], adv[ct], pd);
        }
#pragma unroll
        for (int m = 8; m >= 1; m >>= 1) {     // reduce over lr (16 lanes)
            ps += __shfl_xor(ps, m);
            pd += __shfl_xor(pd, m);
        }
        int n = n0 + w * 16 + lg * 4 + reg;
        if (n < NN) {
#pragma unroll
            for (int ct = 0; ct < 8; ++ct)
                h2bf[(size_t)n * 128 + ct * 16 + lr] = f2bf(acc[ct][reg]);
            if (lr == 0) { asrc[n] = ps; adst[n] = pd; }
        }
    }
}

// ---- layer2 gather-aggregate: one wave per node, 2 nodes/block, heads=1 ----
__global__ __launch_bounds__(128) void k_agg2w(
        const int* __restrict__ off, const int* __restrict__ csr,
        const float* __restrict__ asrc, const float* __restrict__ adst,
        const u16* __restrict__ hbf, float* __restrict__ ob) {
    __shared__ float2 pair[2][DCAP];
    int t = threadIdx.x;
    int wv = t >> 6, l = t & 63;
    int n = blockIdx.x * 2 + wv;
    if (n >= NN) return;
    int e0 = off[n], deg = off[n + 1] - e0;
    float ad = adst[n];
    float a0 = 0.f, a1 = 0.f, inv;
    const char* hc = (const char*)hbf + 4 * l;

    if (deg <= DCAP) {
        float mymax = -1e30f;
        for (int e = l; e < deg; e += 64) {
            int s = csr[e0 + e];
            float al = lrelu(asrc[s] + ad);
            pair[wv][e] = make_float2(al, __int_as_float(s << 8));
            mymax = fmaxf(mymax, al);
        }
#pragma unroll
        for (int m = 32; m >= 1; m >>= 1) mymax = fmaxf(mymax, __shfl_xor(mymax, m));
        float myden = 0.f;
        for (int e = l; e < deg; e += 64) {
            float ex = __expf(pair[wv][e].x - mymax);
            pair[wv][e].x = ex;
            myden += ex;
        }
#pragma unroll
        for (int m = 32; m >= 1; m >>= 1) myden += __shfl_xor(myden, m);
        inv = 1.f / (myden + 1e-16f);
#pragma unroll 4
        for (int e = 0; e < deg; ++e) {
            float2 p = pair[wv][e];
            u32 hw = *(const u32*)(hc + (size_t)(u32)__float_as_int(p.y));
            a0 = fmaf(p.x, __uint_as_float(hw << 16), a0);
            a1 = fmaf(p.x, __uint_as_float(hw & 0xFFFF0000u), a1);
        }
    } else {
        float amax = -1e30f;
        for (int e = e0; e < e0 + deg; ++e)
            amax = fmaxf(amax, lrelu(asrc[csr[e]] + ad));
        float den = 0.f;
        for (int e = e0; e < e0 + deg; ++e) {
            int s = csr[e];
            float ex = __expf(lrelu(asrc[s] + ad) - amax);
            den += ex;
            u32 hw = *(const u32*)(hc + (size_t)((u32)s << 8));
            a0 = fmaf(ex, __uint_as_float(hw << 16), a0);
            a1 = fmaf(ex, __uint_as_float(hw & 0xFFFF0000u), a1);
        }
        inv = 1.f / (den + 1e-16f);
    }
    *(float2*)(ob + (size_t)n * 128 + 2 * l) = make_float2(a0 * inv, a1 * inv);
}

// ---- final: mean over nodes, d_out pre-set to b2 ----
__global__ __launch_bounds__(128) void k_final(const float* __restrict__ ob,
                                               float* __restrict__ out) {
    int c = threadIdx.x;
    float acc = 0.f;
    for (int n = blockIdx.x; n < NN; n += gridDim.x) acc += ob[n * 128 + c];
    atomicAdd(out + c, acc * (1.0f / NN));
}

extern "C" void kernel_launch(void* const* d_in, const int* in_sizes, int n_in,
                              void* d_out, int out_size, void* d_ws, size_t ws_size,
                              hipStream_t stream) {
    const float* x   = (const float*)d_in[0];
    const int*   ei  = (const int*)d_in[1];
    const float* W1  = (const float*)d_in[2];
    const float* as1 = (const float*)d_in[3];
    const float* ad1 = (const float*)d_in[4];
    const float* b1  = (const float*)d_in[5];
    const float* W2  = (const float*)d_in[6];
    const float* as2 = (const float*)d_in[7];
    const float* ad2 = (const float*)d_in[8];
    const float* b2  = (const float*)d_in[9];
    float* out = (float*)d_out;

    char* ws    = (char*)d_ws;
    u16*  hbf   = (u16*)ws;                              // NN*128 bf16 (h1, then h2)
    u32*  x2bf  = (u32*)(hbf + (size_t)NN * 128);        // NN*64 packed bf16 x2
    float* ob   = (float*)(x2bf + (size_t)NN * 64);      // NN*128 f32 (out2)
    float* asr1 = ob + (size_t)NN * 128;                 // NN*4
    float* adt1 = asr1 + NN * 4;                         // NN*4
    float* asr2 = adt1 + NN * 4;                         // NN
    float* adt2 = asr2 + NN;                             // NN
    int* deg    = (int*)(adt2 + NN);                     // NN
    int* off    = deg + NN;                              // NN+1
    int* cur    = off + NN + 1;                          // NN
    int* bsum   = cur + NN;                              // NBLK
    int* csr    = bsum + NBLK;                           // ET
    u16* w2t    = (u16*)(csr + ET);                      // 128*128 bf16

    // CSR build (shared by both layers) + W2 bf16 transpose
    k_init<<<(NN + 255) / 256, 256, 0, stream>>>(deg, b2, out, W2, w2t);
    k_deg<<<(ET + 255) / 256, 256, 0, stream>>>(ei, deg);
    k_scan_a<<<NBLK, SCAN_B, 0, stream>>>(deg, off, bsum);
    k_scan_b<<<1, SCAN_B, 0, stream>>>(bsum, off);
    k_scan_c<<<NBLK, SCAN_B, 0, stream>>>(off, bsum, cur);
    k_fill<<<(ET + 255) / 256, 256, 0, stream>>>(ei, cur, csr);

    // layer 1
    k_node1<<<(NN + 3) / 4, 512, 0, stream>>>(x, W1, as1, ad1, hbf, asr1, adt1);
    k_agg1w<<<(NN + 1) / 2, 128, 0, stream>>>(off, csr, asr1, adt1, hbf, b1, x2bf);

    // layer 2: MFMA GEMM reads x2bf, writes hbf(h2 bf16) + attn dots
    k_node2m<<<(NN + 63) / 64, 256, 0, stream>>>(x2bf, w2t, as2, ad2, hbf, asr2, adt2);
    k_agg2w<<<(NN + 1) / 2, 128, 0, stream>>>(off, csr, asr2, adt2, hbf, ob);

    // mean pool (+b2 already in out)
    k_final<<<256, 128, 0, stream>>>(ob, out);
}

// Round 11
// 259.969 us; speedup vs baseline: 1.3704x; 1.0264x over previous
//
#include <hip/hip_runtime.h>

#define NN 50000
#define NE 800000
#define ET (NE + NN)   // 850000 edges incl. self-loops
#define SCAN_B 256
#define NBLK ((NN + SCAN_B - 1) / SCAN_B)   // 196
#define DCAP 128       // max degree on fast path (Poisson(16)+1: max ~50)

typedef unsigned short u16;
typedef unsigned int u32;
typedef __attribute__((ext_vector_type(8))) short bf16x8;
typedef __attribute__((ext_vector_type(4))) float f32x4;

__device__ __forceinline__ float lrelu(float a) { return a > 0.f ? a : 0.2f * a; }
// f32 -> bf16 bits, round-to-nearest-even
__device__ __forceinline__ u16 f2bf(float f) {
    u32 b = __float_as_uint(f);
    b += 0x7FFFu + ((b >> 16) & 1u);
    return (u16)(b >> 16);
}
__device__ __forceinline__ float bf2f(u16 u) {
    return __uint_as_float(((u32)u) << 16);
}

// ---- init: zero degrees, d_out = b2, W2 -> bf16 transposed [col][k] ----
__global__ void k_init(int* __restrict__ deg, const float* __restrict__ b2,
                       float* __restrict__ out, const float* __restrict__ W2,
                       u16* __restrict__ w2t) {
    int i = blockIdx.x * blockDim.x + threadIdx.x;
    if (i < NN)  deg[i] = 0;
    if (i < 128) out[i] = b2[i];
    if (i < 128 * 128) {
        int k = i >> 7, c = i & 127;
        w2t[c * 128 + k] = f2bf(W2[i]);
    }
}

// ---- CSR build: degree count (atomic without return = fire-and-forget) ----
__global__ void k_deg(const int* __restrict__ ei, int* __restrict__ deg) {
    int e = blockIdx.x * blockDim.x + threadIdx.x;
    if (e >= ET) return;
    int d = (e < NE) ? ei[NE + e] : e - NE;
    atomicAdd(deg + d, 1);
}

// ---- scan stage A ----
__global__ __launch_bounds__(SCAN_B) void k_scan_a(const int* __restrict__ deg,
                                                   int* __restrict__ off,
                                                   int* __restrict__ bsum) {
    __shared__ int sh[SCAN_B];
    int t = threadIdx.x, i = blockIdx.x * SCAN_B + t;
    int v = (i < NN) ? deg[i] : 0;
    sh[t] = v;
    __syncthreads();
#pragma unroll
    for (int s = 1; s < SCAN_B; s <<= 1) {
        int u = (t >= s) ? sh[t - s] : 0;
        __syncthreads();
        sh[t] += u;
        __syncthreads();
    }
    if (i < NN) off[i] = sh[t] - v;
    if (t == SCAN_B - 1) bsum[blockIdx.x] = sh[t];
}

// ---- scan stage B ----
__global__ __launch_bounds__(SCAN_B) void k_scan_b(int* __restrict__ bsum,
                                                   int* __restrict__ off) {
    __shared__ int sh[SCAN_B];
    int t = threadIdx.x;
    int v = (t < NBLK) ? bsum[t] : 0;
    sh[t] = v;
    __syncthreads();
#pragma unroll
    for (int s = 1; s < SCAN_B; s <<= 1) {
        int u = (t >= s) ? sh[t - s] : 0;
        __syncthreads();
        sh[t] += u;
        __syncthreads();
    }
    if (t < NBLK) bsum[t] = sh[t] - v;
    if (t == 0) off[NN] = ET;
}

// ---- scan stage C ----
__global__ __launch_bounds__(SCAN_B) void k_scan_c(int* __restrict__ off,
                                                   const int* __restrict__ bsum,
                                                   int* __restrict__ cur) {
    int i = blockIdx.x * SCAN_B + threadIdx.x;
    if (i >= NN) return;
    int o = off[i] + bsum[blockIdx.x];
    off[i] = o;
    cur[i] = o;
}

// ---- CSR fill: 4 edges per thread (ILP on the atomic round-trip).
//      NE and ET are both multiples of 4 -> chunks never straddle the
//      self-loop boundary and never need a tail guard. ----
__global__ __launch_bounds__(256) void k_fill(const int* __restrict__ ei,
                                              int* __restrict__ cur,
                                              int* __restrict__ csr) {
    int e0 = (blockIdx.x * blockDim.x + threadIdx.x) * 4;
    if (e0 >= ET) return;
    int s[4], d[4];
    if (e0 < NE) {
        int4 sv = *(const int4*)(ei + e0);
        int4 dv = *(const int4*)(ei + NE + e0);
        s[0] = sv.x; s[1] = sv.y; s[2] = sv.z; s[3] = sv.w;
        d[0] = dv.x; d[1] = dv.y; d[2] = dv.z; d[3] = dv.w;
    } else {
#pragma unroll
        for (int j = 0; j < 4; ++j) { s[j] = d[j] = e0 + j - NE; }
    }
    int p[4];
#pragma unroll
    for (int j = 0; j < 4; ++j) p[j] = atomicAdd(cur + d[j], 1);
#pragma unroll
    for (int j = 0; j < 4; ++j) csr[p[j]] = s[j];
}

// ---- layer1 node transform: 4 nodes per block ----
__global__ __launch_bounds__(512) void k_node1(
        const float* __restrict__ x, const float* __restrict__ W1,
        const float* __restrict__ as1, const float* __restrict__ ad1,
        u16* __restrict__ hbf, float* __restrict__ asrc, float* __restrict__ adst) {
    int t = threadIdx.x;
    int n = blockIdx.x * 4 + (t >> 7);
    int c = t & 127;
    if (n >= NN) return;
    float x0 = x[2 * n], x1 = x[2 * n + 1];
    float hv = fmaf(x0, W1[c], x1 * W1[128 + c]);
    hbf[(size_t)n * 128 + c] = f2bf(hv);
    float ps = hv * as1[c], pd = hv * ad1[c];
#pragma unroll
    for (int m = 16; m >= 1; m >>= 1) {
        ps += __shfl_xor(ps, m);
        pd += __shfl_xor(pd, m);
    }
    if ((c & 31) == 0) {
        int hd = c >> 5;
        asrc[n * 4 + hd] = ps;
        adst[n * 4 + hd] = pd;
    }
}

// ---- layer1 gather-aggregate: one wave per node, 2 nodes/block, heads=4.
//      No barriers (waves independent; in-wave LDS ops are in program order).
//      Phase B: 2 packed bf16 channels per thread via one u32 load.
//      Epilogue fuses relu(out1+b1) -> packed bf16 x2 for the MFMA GEMM. ----
__global__ __launch_bounds__(128) void k_agg1w(
        const int* __restrict__ off, const int* __restrict__ csr,
        const float* __restrict__ asrc, const float* __restrict__ adst,
        const u16* __restrict__ hbf, const float* __restrict__ b1,
        u32* __restrict__ x2bf) {
    __shared__ float2 pair[2][4][DCAP];    // [wave][head][edge] {ex, bytes(src<<8)}
    int t = threadIdx.x;
    int wv = t >> 6, l = t & 63;
    int n = blockIdx.x * 2 + wv;
    if (n >= NN) return;                   // whole wave exits; no barriers anywhere
    int hd = l >> 4, li = l & 15;          // head, lane-in-head
    int e0 = off[n], deg = off[n + 1] - e0;
    float ad = adst[n * 4 + hd];
    float a0 = 0.f, a1 = 0.f, inv;
    const char* hc = (const char*)hbf + 4 * l;   // this thread's 2-channel base

    if (deg <= DCAP) {
        float mymax = -1e30f;
        for (int e = li; e < deg; e += 16) {
            int s = csr[e0 + e];
            float al = lrelu(asrc[s * 4 + hd] + ad);
            pair[wv][hd][e] = make_float2(al, __int_as_float(s << 8));
            mymax = fmaxf(mymax, al);
        }
#pragma unroll
        for (int m = 8; m >= 1; m >>= 1) mymax = fmaxf(mymax, __shfl_xor(mymax, m));
        float myden = 0.f;
        for (int e = li; e < deg; e += 16) {
            float ex = __expf(pair[wv][hd][e].x - mymax);
            pair[wv][hd][e].x = ex;
            myden += ex;
        }
#pragma unroll
        for (int m = 8; m >= 1; m >>= 1) myden += __shfl_xor(myden, m);
        inv = 1.f / (myden + 1e-16f);
#pragma unroll 4
        for (int e = 0; e < deg; ++e) {
            float2 p = pair[wv][hd][e];
            u32 hw = *(const u32*)(hc + (size_t)(u32)__float_as_int(p.y));
            a0 = fmaf(p.x, __uint_as_float(hw << 16), a0);
            a1 = fmaf(p.x, __uint_as_float(hw & 0xFFFF0000u), a1);
        }
    } else {
        // fallback (never for Poisson(16); correctness guarantee)
        float amax = -1e30f;
        for (int e = e0; e < e0 + deg; ++e)
            amax = fmaxf(amax, lrelu(asrc[csr[e] * 4 + hd] + ad));
        float den = 0.f;
        for (int e = e0; e < e0 + deg; ++e) {
            int s = csr[e];
            float ex = __expf(lrelu(asrc[s * 4 + hd] + ad) - amax);
            den += ex;
            u32 hw = *(const u32*)(hc + (size_t)((u32)s << 8));
            a0 = fmaf(ex, __uint_as_float(hw << 16), a0);
            a1 = fmaf(ex, __uint_as_float(hw & 0xFFFF0000u), a1);
        }
        inv = 1.f / (den + 1e-16f);
    }
    float2 bb = *(const float2*)(b1 + 2 * l);
    float v0 = fmaxf(fmaf(a0, inv, bb.x), 0.f);
    float v1 = fmaxf(fmaf(a1, inv, bb.y), 0.f);
    x2bf[(size_t)n * 64 + l] = (u32)f2bf(v0) | ((u32)f2bf(v1) << 16);
}

// ---- layer2 node transform via MFMA bf16:
//      h2 = x2@W2 (x2 already bf16-packed from agg1w); h2 out bf16 + attn dots.
//      block 256 thr / 4 waves; tile 64 rows x 128 cols; K=128 in LDS.
//      LDS XOR-swizzle: byte ^= (row&7)<<4. ----
__global__ __launch_bounds__(256) void k_node2m(
        const u32* __restrict__ x2bf,
        const u16* __restrict__ w2t, const float* __restrict__ as2,
        const float* __restrict__ ad2, u16* __restrict__ h2bf,
        float* __restrict__ asrc, float* __restrict__ adst) {
    __shared__ u16 xt[64 * 128];    // 16 KB, x-tile bf16, swizzled rows
    __shared__ u16 wt[128 * 128];   // 32 KB, W2T [col][k] bf16, swizzled rows
    int t = threadIdx.x;
    int n0 = blockIdx.x * 64;

    // stage x-tile: pure swizzled copy (bias/relu/bf16 already applied)
    // xt geometry: 64 rows x 256 B = 1024 16B chunks
#pragma unroll
    for (int i = 0; i < 4; ++i) {
        int c8 = t + i * 256;
        int r = c8 >> 4, k8 = c8 & 15;
        int n = n0 + r;
        uint4 v = make_uint4(0, 0, 0, 0);
        if (n < NN) v = *(const uint4*)(x2bf + (size_t)n * 64 + k8 * 4);
        int offb = r * 256 + ((k8 * 16) ^ ((r & 7) << 4));
        *(uint4*)((char*)xt + offb) = v;
    }
    // stage W2T tile: 128 rows x 256 B = 2048 16B chunks
#pragma unroll
    for (int i = 0; i < 8; ++i) {
        int c8 = t + i * 256;
        int row = c8 >> 4, k8 = c8 & 15;
        uint4 wv = *(const uint4*)(w2t + row * 128 + k8 * 8);
        int offb = row * 256 + ((k8 * 16) ^ ((row & 7) << 4));
        *(uint4*)((char*)wt + offb) = wv;
    }
    __syncthreads();

    int l = t & 63, w = t >> 6;
    int lr = l & 15, lg = l >> 4;              // lane row-in-tile, k-group

    // A fragments: row = w*16 + lr, k = kc*32 + lg*8 + j  (contiguous 16B)
    bf16x8 afr[4];
    int ar = w * 16 + lr;
#pragma unroll
    for (int kc = 0; kc < 4; ++kc) {
        int kbyte = kc * 64 + lg * 16;
        afr[kc] = *(const bf16x8*)((char*)xt + ar * 256 + (kbyte ^ ((ar & 7) << 4)));
    }

    f32x4 acc[8];
#pragma unroll
    for (int ct = 0; ct < 8; ++ct) {
        f32x4 c = {0.f, 0.f, 0.f, 0.f};
        int br = ct * 16 + lr;                 // B: col = ct*16+lr, k contiguous
#pragma unroll
        for (int kc = 0; kc < 4; ++kc) {
            int kbyte = kc * 64 + lg * 16;
            bf16x8 b = *(const bf16x8*)((char*)wt + br * 256 + (kbyte ^ ((br & 7) << 4)));
            c = __builtin_amdgcn_mfma_f32_16x16x32_bf16(afr[kc], b, c, 0, 0, 0);
        }
        acc[ct] = c;
    }

    // epilogue: C/D layout col = lr, row = lg*4 + reg  [m89]
    float asv[8], adv[8];
#pragma unroll
    for (int ct = 0; ct < 8; ++ct) {
        asv[ct] = as2[ct * 16 + lr];
        adv[ct] = ad2[ct * 16 + lr];
    }
#pragma unroll
    for (int reg = 0; reg < 4; ++reg) {
        float ps = 0.f, pd = 0.f;
#pragma unroll
        for (int ct = 0; ct < 8; ++ct) {
            ps = fmaf(acc[ct][reg], asv[ct], ps);
            pd = fmaf(acc[ct][reg], adv[ct], pd);
        }
#pragma unroll
        for (int m = 8; m >= 1; m >>= 1) {     // reduce over lr (16 lanes)
            ps += __shfl_xor(ps, m);
            pd += __shfl_xor(pd, m);
        }
        int n = n0 + w * 16 + lg * 4 + reg;
        if (n < NN) {
#pragma unroll
            for (int ct = 0; ct < 8; ++ct)
                h2bf[(size_t)n * 128 + ct * 16 + lr] = f2bf(acc[ct][reg]);
            if (lr == 0) { asrc[n] = ps; adst[n] = pd; }
        }
    }
}

// ---- layer2 gather-aggregate: one wave per node, 2 nodes/block, heads=1 ----
__global__ __launch_bounds__(128) void k_agg2w(
        const int* __restrict__ off, const int* __restrict__ csr,
        const float* __restrict__ asrc, const float* __restrict__ adst,
        const u16* __restrict__ hbf, float* __restrict__ ob) {
    __shared__ float2 pair[2][DCAP];
    int t = threadIdx.x;
    int wv = t >> 6, l = t & 63;
    int n = blockIdx.x * 2 + wv;
    if (n >= NN) return;
    int e0 = off[n], deg = off[n + 1] - e0;
    float ad = adst[n];
    float a0 = 0.f, a1 = 0.f, inv;
    const char* hc = (const char*)hbf + 4 * l;

    if (deg <= DCAP) {
        float mymax = -1e30f;
        for (int e = l; e < deg; e += 64) {
            int s = csr[e0 + e];
            float al = lrelu(asrc[s] + ad);
            pair[wv][e] = make_float2(al, __int_as_float(s << 8));
            mymax = fmaxf(mymax, al);
        }
#pragma unroll
        for (int m = 32; m >= 1; m >>= 1) mymax = fmaxf(mymax, __shfl_xor(mymax, m));
        float myden = 0.f;
        for (int e = l; e < deg; e += 64) {
            float ex = __expf(pair[wv][e].x - mymax);
            pair[wv][e].x = ex;
            myden += ex;
        }
#pragma unroll
        for (int m = 32; m >= 1; m >>= 1) myden += __shfl_xor(myden, m);
        inv = 1.f / (myden + 1e-16f);
#pragma unroll 4
        for (int e = 0; e < deg; ++e) {
            float2 p = pair[wv][e];
            u32 hw = *(const u32*)(hc + (size_t)(u32)__float_as_int(p.y));
            a0 = fmaf(p.x, __uint_as_float(hw << 16), a0);
            a1 = fmaf(p.x, __uint_as_float(hw & 0xFFFF0000u), a1);
        }
    } else {
        float amax = -1e30f;
        for (int e = e0; e < e0 + deg; ++e)
            amax = fmaxf(amax, lrelu(asrc[csr[e]] + ad));
        float den = 0.f;
        for (int e = e0; e < e0 + deg; ++e) {
            int s = csr[e];
            float ex = __expf(lrelu(asrc[s] + ad) - amax);
            den += ex;
            u32 hw = *(const u32*)(hc + (size_t)((u32)s << 8));
            a0 = fmaf(ex, __uint_as_float(hw << 16), a0);
            a1 = fmaf(ex, __uint_as_float(hw & 0xFFFF0000u), a1);
        }
        inv = 1.f / (den + 1e-16f);
    }
    *(float2*)(ob + (size_t)n * 128 + 2 * l) = make_float2(a0 * inv, a1 * inv);
}

// ---- final: mean over nodes, d_out pre-set to b2 ----
__global__ __launch_bounds__(128) void k_final(const float* __restrict__ ob,
                                               float* __restrict__ out) {
    int c = threadIdx.x;
    float acc = 0.f;
    for (int n = blockIdx.x; n < NN; n += gridDim.x) acc += ob[n * 128 + c];
    atomicAdd(out + c, acc * (1.0f / NN));
}

extern "C" void kernel_launch(void* const* d_in, const int* in_sizes, int n_in,
                              void* d_out, int out_size, void* d_ws, size_t ws_size,
                              hipStream_t stream) {
    const float* x   = (const float*)d_in[0];
    const int*   ei  = (const int*)d_in[1];
    const float* W1  = (const float*)d_in[2];
    const float* as1 = (const float*)d_in[3];
    const float* ad1 = (const float*)d_in[4];
    const float* b1  = (const float*)d_in[5];
    const float* W2  = (const float*)d_in[6];
    const float* as2 = (const float*)d_in[7];
    const float* ad2 = (const float*)d_in[8];
    const float* b2  = (const float*)d_in[9];
    float* out = (float*)d_out;

    char* ws    = (char*)d_ws;
    u16*  hbf   = (u16*)ws;                              // NN*128 bf16 (h1, then h2)
    u32*  x2bf  = (u32*)(hbf + (size_t)NN * 128);        // NN*64 packed bf16 x2
    float* ob   = (float*)(x2bf + (size_t)NN * 64);      // NN*128 f32 (out2)
    float* asr1 = ob + (size_t)NN * 128;                 // NN*4
    float* adt1 = asr1 + NN * 4;                         // NN*4
    float* asr2 = adt1 + NN * 4;                         // NN
    float* adt2 = asr2 + NN;                             // NN
    int* deg    = (int*)(adt2 + NN);                     // NN
    int* off    = deg + NN;                              // NN+1
    int* cur    = off + NN + 1;                          // NN
    int* bsum   = cur + NN;                              // NBLK
    int* csr    = bsum + NBLK;                           // ET
    u16* w2t    = (u16*)(csr + ET);                      // 128*128 bf16

    // CSR build (shared by both layers) + W2 bf16 transpose
    k_init<<<(NN + 255) / 256, 256, 0, stream>>>(deg, b2, out, W2, w2t);
    k_deg<<<(ET + 255) / 256, 256, 0, stream>>>(ei, deg);
    k_scan_a<<<NBLK, SCAN_B, 0, stream>>>(deg, off, bsum);
    k_scan_b<<<1, SCAN_B, 0, stream>>>(bsum, off);
    k_scan_c<<<NBLK, SCAN_B, 0, stream>>>(off, bsum, cur);
    k_fill<<<(ET / 4 + 255) / 256, 256, 0, stream>>>(ei, cur, csr);

    // layer 1
    k_node1<<<(NN + 3) / 4, 512, 0, stream>>>(x, W1, as1, ad1, hbf, asr1, adt1);
    k_agg1w<<<(NN + 1) / 2, 128, 0, stream>>>(off, csr, asr1, adt1, hbf, b1, x2bf);

    // layer 2: MFMA GEMM reads x2bf, writes hbf(h2 bf16) + attn dots
    k_node2m<<<(NN + 63) / 64, 256, 0, stream>>>(x2bf, w2t, as2, ad2, hbf, asr2, adt2);
    k_agg2w<<<(NN + 1) / 2, 128, 0, stream>>>(off, csr, asr2, adt2, hbf, ob);

    // mean pool (+b2 already in out)
    k_final<<<256, 128, 0, stream>>>(ob, out);
}

// Round 12
// 225.821 us; speedup vs baseline: 1.5777x; 1.1512x over previous
//
#include <hip/hip_runtime.h>

#define NN 50000
#define NE 800000
#define ET (NE + NN)   // 850000 edges incl. self-loops
#define SCAN_B 256
#define NBLK ((NN + SCAN_B - 1) / SCAN_B)   // 196
#define DCAP 128       // max degree on fast path (Poisson(16)+1: max ~50)
#define EPW 4096       // edges per k_part workgroup
#define NWGP ((ET + EPW - 1) / EPW)         // 208
#define NB 196         // buckets = dst>>8
#define BCAP 6144      // staging capacity per bucket (mean 4337, sd ~66)

typedef unsigned short u16;
typedef unsigned int u32;
typedef unsigned char u8;
typedef __attribute__((ext_vector_type(8))) short bf16x8;
typedef __attribute__((ext_vector_type(4))) float f32x4;

__device__ __forceinline__ float lrelu(float a) { return a > 0.f ? a : 0.2f * a; }
// f32 -> bf16 bits, round-to-nearest-even
__device__ __forceinline__ u16 f2bf(float f) {
    u32 b = __float_as_uint(f);
    b += 0x7FFFu + ((b >> 16) & 1u);
    return (u16)(b >> 16);
}
__device__ __forceinline__ float bf2f(u16 u) {
    return __uint_as_float(((u32)u) << 16);
}

// ---- init: zero deg/bcur/ovf, d_out = b2, W2 -> bf16 transposed [col][k] ----
__global__ void k_init(int* __restrict__ deg, const float* __restrict__ b2,
                       float* __restrict__ out, const float* __restrict__ W2,
                       u16* __restrict__ w2t, u32* __restrict__ bcur,
                       u32* __restrict__ ovf) {
    int i = blockIdx.x * blockDim.x + threadIdx.x;
    if (i < NN)  deg[i] = 0;
    if (i < 128) out[i] = b2[i];
    if (i < 256) bcur[i] = 0;
    if (i == 0)  *ovf = 0;
    if (i < 128 * 128) {
        int k = i >> 7, c = i & 127;
        w2t[c * 128 + k] = f2bf(W2[i]);
    }
}

// ---- pass A: fused degree count + bucket partition (LDS counting sort).
//      Writes (dst<<16|src) pairs bucket-contiguously -> coalesced. ----
__global__ __launch_bounds__(256) void k_part(
        const int* __restrict__ ei, int* __restrict__ deg,
        u32* __restrict__ bcur, u32* __restrict__ stg,
        u32* __restrict__ stg2, u32* __restrict__ ovf) {
    __shared__ u32 lcnt[256], sc[256], lbase[256], gbase[256];
    __shared__ u32 lpair[EPW];
    __shared__ u8  lbkt[EPW];
    int t = threadIdx.x;
    int e0 = blockIdx.x * EPW;
    lcnt[t] = 0;
    __syncthreads();

    u32 pr[16]; u16 rk[16]; u8 bk[16]; bool vd[16];
#pragma unroll
    for (int j = 0; j < 16; ++j) {
        int e = e0 + j * 256 + t;
        vd[j] = (e < ET);
        if (vd[j]) {
            int s, d;
            if (e < NE) { s = ei[e]; d = ei[NE + e]; } else { s = d = e - NE; }
            atomicAdd(deg + d, 1);                 // fused degree histogram
            pr[j] = ((u32)d << 16) | (u32)s;
            int b = d >> 8;
            bk[j] = (u8)b;
            rk[j] = (u16)atomicAdd(&lcnt[b], 1u);
        }
    }
    __syncthreads();
    // exclusive scan lcnt -> lbase (Hillis-Steele, lcnt preserved)
    u32 v = lcnt[t];
    sc[t] = v;
    __syncthreads();
#pragma unroll
    for (int st = 1; st < 256; st <<= 1) {
        u32 u = (t >= st) ? sc[t - st] : 0;
        __syncthreads();
        sc[t] += u;
        __syncthreads();
    }
    lbase[t] = sc[t] - v;
    gbase[t] = atomicAdd(&bcur[t], v);             // global base per bucket
    __syncthreads();
#pragma unroll
    for (int j = 0; j < 16; ++j) if (vd[j]) {
        u32 idx = lbase[bk[j]] + rk[j];
        lpair[idx] = pr[j];
        lbkt[idx]  = bk[j];
    }
    __syncthreads();
    int nloc = lbase[255] + lcnt[255];             // total valid this block
    for (int i = t; i < nloc; i += 256) {
        u32 b = lbkt[i];
        u32 g = gbase[b] + (i - lbase[b]);
        u32 p = lpair[i];
        if (g < BCAP) stg[(size_t)b * BCAP + g] = p;
        else { u32 o = atomicAdd(ovf, 1u); if (o < 4096) stg2[o] = p; }
    }
}

// ---- scan stage A ----
__global__ __launch_bounds__(SCAN_B) void k_scan_a(const int* __restrict__ deg,
                                                   int* __restrict__ off,
                                                   int* __restrict__ bsum) {
    __shared__ int sh[SCAN_B];
    int t = threadIdx.x, i = blockIdx.x * SCAN_B + t;
    int v = (i < NN) ? deg[i] : 0;
    sh[t] = v;
    __syncthreads();
#pragma unroll
    for (int s = 1; s < SCAN_B; s <<= 1) {
        int u = (t >= s) ? sh[t - s] : 0;
        __syncthreads();
        sh[t] += u;
        __syncthreads();
    }
    if (i < NN) off[i] = sh[t] - v;
    if (t == SCAN_B - 1) bsum[blockIdx.x] = sh[t];
}

// ---- scan stage B ----
__global__ __launch_bounds__(SCAN_B) void k_scan_b(int* __restrict__ bsum,
                                                   int* __restrict__ off) {
    __shared__ int sh[SCAN_B];
    int t = threadIdx.x;
    int v = (t < NBLK) ? bsum[t] : 0;
    sh[t] = v;
    __syncthreads();
#pragma unroll
    for (int s = 1; s < SCAN_B; s <<= 1) {
        int u = (t >= s) ? sh[t - s] : 0;
        __syncthreads();
        sh[t] += u;
        __syncthreads();
    }
    if (t < NBLK) bsum[t] = sh[t] - v;
    if (t == 0) off[NN] = ET;
}

// ---- scan stage C ----
__global__ __launch_bounds__(SCAN_B) void k_scan_c(int* __restrict__ off,
                                                   const int* __restrict__ bsum) {
    int i = blockIdx.x * SCAN_B + threadIdx.x;
    if (i >= NN) return;
    off[i] += bsum[blockIdx.x];
}

// ---- pass B: one block per bucket; LDS cursors from off; coalesced csr write ----
__global__ __launch_bounds__(256) void k_place(
        const int* __restrict__ off, const u32* __restrict__ bcur,
        const u32* __restrict__ stg, const u32* __restrict__ stg2,
        const u32* __restrict__ ovf, u16* __restrict__ csr16) {
    __shared__ u32 lcur[256];
    __shared__ u16 lcsr[BCAP];
    int b = blockIdx.x, t = threadIdx.x;
    int n0 = b << 8;
    int n1 = min(n0 + 256, NN);
    int S0 = off[n0];
    int span = off[n1] - S0;
    if (n0 + t < n1) lcur[t] = (u32)(off[n0 + t] - S0);
    __syncthreads();
    u32 cnt = bcur[b];
    u32 cmain = min(cnt, (u32)BCAP);
    bool direct = (span > BCAP);                   // pathological only
    for (u32 i = t; i < cmain; i += 256) {
        u32 p = stg[(size_t)b * BCAP + i];
        u32 nrel = (p >> 16) & 255u;
        u32 r = atomicAdd(&lcur[nrel], 1u);
        if (direct) csr16[S0 + r] = (u16)(p & 0xFFFFu);
        else        lcsr[r] = (u16)(p & 0xFFFFu);
    }
    if (cnt > cmain) {                             // staged overflow (≈never)
        u32 no = min(*ovf, 4096u);
        for (u32 i = t; i < no; i += 256) {
            u32 p = stg2[i];
            if ((p >> 24) == (u32)b) {
                u32 nrel = (p >> 16) & 255u;
                u32 r = atomicAdd(&lcur[nrel], 1u);
                if (direct) csr16[S0 + r] = (u16)(p & 0xFFFFu);
                else        lcsr[r] = (u16)(p & 0xFFFFu);
            }
        }
    }
    __syncthreads();
    if (!direct)
        for (int i = t; i < span; i += 256) csr16[S0 + i] = lcsr[i];
}

// ---- layer1 node transform: 4 nodes per block ----
__global__ __launch_bounds__(512) void k_node1(
        const float* __restrict__ x, const float* __restrict__ W1,
        const float* __restrict__ as1, const float* __restrict__ ad1,
        u16* __restrict__ hbf, float* __restrict__ asrc, float* __restrict__ adst) {
    int t = threadIdx.x;
    int n = blockIdx.x * 4 + (t >> 7);
    int c = t & 127;
    if (n >= NN) return;
    float x0 = x[2 * n], x1 = x[2 * n + 1];
    float hv = fmaf(x0, W1[c], x1 * W1[128 + c]);
    hbf[(size_t)n * 128 + c] = f2bf(hv);
    float ps = hv * as1[c], pd = hv * ad1[c];
#pragma unroll
    for (int m = 16; m >= 1; m >>= 1) {
        ps += __shfl_xor(ps, m);
        pd += __shfl_xor(pd, m);
    }
    if ((c & 31) == 0) {
        int hd = c >> 5;
        asrc[n * 4 + hd] = ps;
        adst[n * 4 + hd] = pd;
    }
}

// ---- layer1 gather-aggregate: one wave per node, 2 nodes/block, heads=4 ----
__global__ __launch_bounds__(128) void k_agg1w(
        const int* __restrict__ off, const u16* __restrict__ csr,
        const float* __restrict__ asrc, const float* __restrict__ adst,
        const u16* __restrict__ hbf, const float* __restrict__ b1,
        u32* __restrict__ x2bf) {
    __shared__ float2 pair[2][4][DCAP];    // [wave][head][edge] {ex, bytes(src<<8)}
    int t = threadIdx.x;
    int wv = t >> 6, l = t & 63;
    int n = blockIdx.x * 2 + wv;
    if (n >= NN) return;                   // whole wave exits; no barriers anywhere
    int hd = l >> 4, li = l & 15;          // head, lane-in-head
    int e0 = off[n], deg = off[n + 1] - e0;
    float ad = adst[n * 4 + hd];
    float a0 = 0.f, a1 = 0.f, inv;
    const char* hc = (const char*)hbf + 4 * l;   // this thread's 2-channel base

    if (deg <= DCAP) {
        float mymax = -1e30f;
        for (int e = li; e < deg; e += 16) {
            int s = csr[e0 + e];
            float al = lrelu(asrc[s * 4 + hd] + ad);
            pair[wv][hd][e] = make_float2(al, __int_as_float(s << 8));
            mymax = fmaxf(mymax, al);
        }
#pragma unroll
        for (int m = 8; m >= 1; m >>= 1) mymax = fmaxf(mymax, __shfl_xor(mymax, m));
        float myden = 0.f;
        for (int e = li; e < deg; e += 16) {
            float ex = __expf(pair[wv][hd][e].x - mymax);
            pair[wv][hd][e].x = ex;
            myden += ex;
        }
#pragma unroll
        for (int m = 8; m >= 1; m >>= 1) myden += __shfl_xor(myden, m);
        inv = 1.f / (myden + 1e-16f);
#pragma unroll 4
        for (int e = 0; e < deg; ++e) {
            float2 p = pair[wv][hd][e];
            u32 hw = *(const u32*)(hc + (size_t)(u32)__float_as_int(p.y));
            a0 = fmaf(p.x, __uint_as_float(hw << 16), a0);
            a1 = fmaf(p.x, __uint_as_float(hw & 0xFFFF0000u), a1);
        }
    } else {
        // fallback (degree overflow; correctness guarantee)
        float amax = -1e30f;
        for (int e = e0; e < e0 + deg; ++e)
            amax = fmaxf(amax, lrelu(asrc[csr[e] * 4 + hd] + ad));
        float den = 0.f;
        for (int e = e0; e < e0 + deg; ++e) {
            int s = csr[e];
            float ex = __expf(lrelu(asrc[s * 4 + hd] + ad) - amax);
            den += ex;
            u32 hw = *(const u32*)(hc + (size_t)((u32)s << 8));
            a0 = fmaf(ex, __uint_as_float(hw << 16), a0);
            a1 = fmaf(ex, __uint_as_float(hw & 0xFFFF0000u), a1);
        }
        inv = 1.f / (den + 1e-16f);
    }
    float2 bb = *(const float2*)(b1 + 2 * l);
    float v0 = fmaxf(fmaf(a0, inv, bb.x), 0.f);
    float v1 = fmaxf(fmaf(a1, inv, bb.y), 0.f);
    x2bf[(size_t)n * 64 + l] = (u32)f2bf(v0) | ((u32)f2bf(v1) << 16);
}

// ---- layer2 node transform via MFMA bf16 (as R9/R10) ----
__global__ __launch_bounds__(256) void k_node2m(
        const u32* __restrict__ x2bf,
        const u16* __restrict__ w2t, const float* __restrict__ as2,
        const float* __restrict__ ad2, u16* __restrict__ h2bf,
        float* __restrict__ asrc, float* __restrict__ adst) {
    __shared__ u16 xt[64 * 128];    // 16 KB, x-tile bf16, swizzled rows
    __shared__ u16 wt[128 * 128];   // 32 KB, W2T [col][k] bf16, swizzled rows
    int t = threadIdx.x;
    int n0 = blockIdx.x * 64;

#pragma unroll
    for (int i = 0; i < 4; ++i) {
        int c8 = t + i * 256;
        int r = c8 >> 4, k8 = c8 & 15;
        int n = n0 + r;
        uint4 v = make_uint4(0, 0, 0, 0);
        if (n < NN) v = *(const uint4*)(x2bf + (size_t)n * 64 + k8 * 4);
        int offb = r * 256 + ((k8 * 16) ^ ((r & 7) << 4));
        *(uint4*)((char*)xt + offb) = v;
    }
#pragma unroll
    for (int i = 0; i < 8; ++i) {
        int c8 = t + i * 256;
        int row = c8 >> 4, k8 = c8 & 15;
        uint4 wv = *(const uint4*)(w2t + row * 128 + k8 * 8);
        int offb = row * 256 + ((k8 * 16) ^ ((row & 7) << 4));
        *(uint4*)((char*)wt + offb) = wv;
    }
    __syncthreads();

    int l = t & 63, w = t >> 6;
    int lr = l & 15, lg = l >> 4;

    bf16x8 afr[4];
    int ar = w * 16 + lr;
#pragma unroll
    for (int kc = 0; kc < 4; ++kc) {
        int kbyte = kc * 64 + lg * 16;
        afr[kc] = *(const bf16x8*)((char*)xt + ar * 256 + (kbyte ^ ((ar & 7) << 4)));
    }

    f32x4 acc[8];
#pragma unroll
    for (int ct = 0; ct < 8; ++ct) {
        f32x4 c = {0.f, 0.f, 0.f, 0.f};
        int br = ct * 16 + lr;
#pragma unroll
        for (int kc = 0; kc < 4; ++kc) {
            int kbyte = kc * 64 + lg * 16;
            bf16x8 b = *(const bf16x8*)((char*)wt + br * 256 + (kbyte ^ ((br & 7) << 4)));
            c = __builtin_amdgcn_mfma_f32_16x16x32_bf16(afr[kc], b, c, 0, 0, 0);
        }
        acc[ct] = c;
    }

    float asv[8], adv[8];
#pragma unroll
    for (int ct = 0; ct < 8; ++ct) {
        asv[ct] = as2[ct * 16 + lr];
        adv[ct] = ad2[ct * 16 + lr];
    }
#pragma unroll
    for (int reg = 0; reg < 4; ++reg) {
        float ps = 0.f, pd = 0.f;
#pragma unroll
        for (int ct = 0; ct < 8; ++ct) {
            ps = fmaf(acc[ct][reg], asv[ct], ps);
            pd = fmaf(acc[ct][reg], adv[ct], pd);
        }
#pragma unroll
        for (int m = 8; m >= 1; m >>= 1) {
            ps += __shfl_xor(ps, m);
            pd += __shfl_xor(pd, m);
        }
        int n = n0 + w * 16 + lg * 4 + reg;
        if (n < NN) {
#pragma unroll
            for (int ct = 0; ct < 8; ++ct)
                h2bf[(size_t)n * 128 + ct * 16 + lr] = f2bf(acc[ct][reg]);
            if (lr == 0) { asrc[n] = ps; adst[n] = pd; }
        }
    }
}

// ---- layer2 gather-aggregate: one wave per node, 2 nodes/block, heads=1 ----
__global__ __launch_bounds__(128) void k_agg2w(
        const int* __restrict__ off, const u16* __restrict__ csr,
        const float* __restrict__ asrc, const float* __restrict__ adst,
        const u16* __restrict__ hbf, float* __restrict__ ob) {
    __shared__ float2 pair[2][DCAP];
    int t = threadIdx.x;
    int wv = t >> 6, l = t & 63;
    int n = blockIdx.x * 2 + wv;
    if (n >= NN) return;
    int e0 = off[n], deg = off[n + 1] - e0;
    float ad = adst[n];
    float a0 = 0.f, a1 = 0.f, inv;
    const char* hc = (const char*)hbf + 4 * l;

    if (deg <= DCAP) {
        float mymax = -1e30f;
        for (int e = l; e < deg; e += 64) {
            int s = csr[e0 + e];
            float al = lrelu(asrc[s] + ad);
            pair[wv][e] = make_float2(al, __int_as_float(s << 8));
            mymax = fmaxf(mymax, al);
        }
#pragma unroll
        for (int m = 32; m >= 1; m >>= 1) mymax = fmaxf(mymax, __shfl_xor(mymax, m));
        float myden = 0.f;
        for (int e = l; e < deg; e += 64) {
            float ex = __expf(pair[wv][e].x - mymax);
            pair[wv][e].x = ex;
            myden += ex;
        }
#pragma unroll
        for (int m = 32; m >= 1; m >>= 1) myden += __shfl_xor(myden, m);
        inv = 1.f / (myden + 1e-16f);
#pragma unroll 4
        for (int e = 0; e < deg; ++e) {
            float2 p = pair[wv][e];
            u32 hw = *(const u32*)(hc + (size_t)(u32)__float_as_int(p.y));
            a0 = fmaf(p.x, __uint_as_float(hw << 16), a0);
            a1 = fmaf(p.x, __uint_as_float(hw & 0xFFFF0000u), a1);
        }
    } else {
        float amax = -1e30f;
        for (int e = e0; e < e0 + deg; ++e)
            amax = fmaxf(amax, lrelu(asrc[csr[e]] + ad));
        float den = 0.f;
        for (int e = e0; e < e0 + deg; ++e) {
            int s = csr[e];
            float ex = __expf(lrelu(asrc[s] + ad) - amax);
            den += ex;
            u32 hw = *(const u32*)(hc + (size_t)((u32)s << 8));
            a0 = fmaf(ex, __uint_as_float(hw << 16), a0);
            a1 = fmaf(ex, __uint_as_float(hw & 0xFFFF0000u), a1);
        }
        inv = 1.f / (den + 1e-16f);
    }
    *(float2*)(ob + (size_t)n * 128 + 2 * l) = make_float2(a0 * inv, a1 * inv);
}

// ---- final: mean over nodes, d_out pre-set to b2 ----
__global__ __launch_bounds__(128) void k_final(const float* __restrict__ ob,
                                               float* __restrict__ out) {
    int c = threadIdx.x;
    float acc = 0.f;
    for (int n = blockIdx.x; n < NN; n += gridDim.x) acc += ob[n * 128 + c];
    atomicAdd(out + c, acc * (1.0f / NN));
}

extern "C" void kernel_launch(void* const* d_in, const int* in_sizes, int n_in,
                              void* d_out, int out_size, void* d_ws, size_t ws_size,
                              hipStream_t stream) {
    const float* x   = (const float*)d_in[0];
    const int*   ei  = (const int*)d_in[1];
    const float* W1  = (const float*)d_in[2];
    const float* as1 = (const float*)d_in[3];
    const float* ad1 = (const float*)d_in[4];
    const float* b1  = (const float*)d_in[5];
    const float* W2  = (const float*)d_in[6];
    const float* as2 = (const float*)d_in[7];
    const float* ad2 = (const float*)d_in[8];
    const float* b2  = (const float*)d_in[9];
    float* out = (float*)d_out;

    char* ws    = (char*)d_ws;
    u16*  hbf   = (u16*)ws;                              // NN*128 bf16 (h1, then h2)
    u32*  x2bf  = (u32*)(hbf + (size_t)NN * 128);        // NN*64 packed bf16 x2
    u32*  stg   = x2bf;                                  // ALIAS: stg dead before x2bf written
    float* ob   = (float*)(x2bf + (size_t)NN * 64);      // NN*128 f32 (out2)
    float* asr1 = ob + (size_t)NN * 128;                 // NN*4
    float* adt1 = asr1 + NN * 4;                         // NN*4
    float* asr2 = adt1 + NN * 4;                         // NN
    float* adt2 = asr2 + NN;                             // NN
    int* deg    = (int*)(adt2 + NN);                     // NN
    int* off    = deg + NN;                              // NN+1
    int* bsum   = off + NN + 1;                          // NBLK
    u16* w2t    = (u16*)(bsum + NBLK);                   // 128*128 bf16
    u32* bcur   = (u32*)(w2t + 128 * 128);               // 256
    u32* ovf    = bcur + 256;                            // 1 (+pad)
    u32* stg2   = ovf + 4;                               // 4096 overflow pairs
    u16* csr16  = (u16*)(stg2 + 4096);                   // ET u16

    // CSR build: fused deg+partition, scan, place
    k_init<<<(NN + 255) / 256, 256, 0, stream>>>(deg, b2, out, W2, w2t, bcur, ovf);
    k_part<<<NWGP, 256, 0, stream>>>(ei, deg, bcur, stg, stg2, ovf);
    k_scan_a<<<NBLK, SCAN_B, 0, stream>>>(deg, off, bsum);
    k_scan_b<<<1, SCAN_B, 0, stream>>>(bsum, off);
    k_scan_c<<<NBLK, SCAN_B, 0, stream>>>(off, bsum);
    k_place<<<NB, 256, 0, stream>>>(off, bcur, stg, stg2, ovf, csr16);

    // layer 1
    k_node1<<<(NN + 3) / 4, 512, 0, stream>>>(x, W1, as1, ad1, hbf, asr1, adt1);
    k_agg1w<<<(NN + 1) / 2, 128, 0, stream>>>(off, csr16, asr1, adt1, hbf, b1, x2bf);

    // layer 2: MFMA GEMM reads x2bf, writes hbf(h2 bf16) + attn dots
    k_node2m<<<(NN + 63) / 64, 256, 0, stream>>>(x2bf, w2t, as2, ad2, hbf, asr2, adt2);
    k_agg2w<<<(NN + 1) / 2, 128, 0, stream>>>(off, csr16, asr2, adt2, hbf, ob);

    // mean pool (+b2 already in out)
    k_final<<<256, 128, 0, stream>>>(ob, out);
}

// Round 13
// 206.991 us; speedup vs baseline: 1.7212x; 1.0910x over previous
//
#include <hip/hip_runtime.h>

#define NN 50000
#define NE 800000
#define ET (NE + NN)   // 850000 edges incl. self-loops
#define SCAN_B 256
#define NBLK ((NN + SCAN_B - 1) / SCAN_B)   // 196
#define DCAP 128       // max degree on fast path (Poisson(16)+1: max ~50)
#define EPW 4096       // edges per k_part workgroup
#define NWGP ((ET + EPW - 1) / EPW)         // 208
#define NB 196         // buckets = dst>>8
#define BCAP 6144      // staging capacity per bucket (mean 4337, sd ~66)

typedef unsigned short u16;
typedef unsigned int u32;
typedef unsigned char u8;
typedef __attribute__((ext_vector_type(8))) short bf16x8;
typedef __attribute__((ext_vector_type(4))) float f32x4;

__device__ __forceinline__ float lrelu(float a) { return a > 0.f ? a : 0.2f * a; }
// f32 -> bf16 bits, round-to-nearest-even
__device__ __forceinline__ u16 f2bf(float f) {
    u32 b = __float_as_uint(f);
    b += 0x7FFFu + ((b >> 16) & 1u);
    return (u16)(b >> 16);
}
__device__ __forceinline__ float bf2f(u16 u) {
    return __uint_as_float(((u32)u) << 16);
}

// ---- init: zero deg/bcur/ovf, d_out = b2, W2 -> bf16 transposed [col][k] ----
__global__ void k_init(int* __restrict__ deg, const float* __restrict__ b2,
                       float* __restrict__ out, const float* __restrict__ W2,
                       u16* __restrict__ w2t, u32* __restrict__ bcur,
                       u32* __restrict__ ovf) {
    int i = blockIdx.x * blockDim.x + threadIdx.x;
    if (i < NN)  deg[i] = 0;
    if (i < 128) out[i] = b2[i];
    if (i < 256) bcur[i] = 0;
    if (i == 0)  *ovf = 0;
    if (i < 128 * 128) {
        int k = i >> 7, c = i & 127;
        w2t[c * 128 + k] = f2bf(W2[i]);
    }
}

// ---- pass A: fused degree count + bucket partition (LDS counting sort).
//      Writes (dst<<16|src) pairs bucket-contiguously -> coalesced. ----
__global__ __launch_bounds__(256) void k_part(
        const int* __restrict__ ei, int* __restrict__ deg,
        u32* __restrict__ bcur, u32* __restrict__ stg,
        u32* __restrict__ stg2, u32* __restrict__ ovf) {
    __shared__ u32 lcnt[256], sc[256], lbase[256], gbase[256];
    __shared__ u32 lpair[EPW];
    __shared__ u8  lbkt[EPW];
    int t = threadIdx.x;
    int e0 = blockIdx.x * EPW;
    lcnt[t] = 0;
    __syncthreads();

    u32 pr[16]; u16 rk[16]; u8 bk[16]; bool vd[16];
#pragma unroll
    for (int j = 0; j < 16; ++j) {
        int e = e0 + j * 256 + t;
        vd[j] = (e < ET);
        if (vd[j]) {
            int s, d;
            if (e < NE) { s = ei[e]; d = ei[NE + e]; } else { s = d = e - NE; }
            atomicAdd(deg + d, 1);                 // fused degree histogram
            pr[j] = ((u32)d << 16) | (u32)s;
            int b = d >> 8;
            bk[j] = (u8)b;
            rk[j] = (u16)atomicAdd(&lcnt[b], 1u);
        }
    }
    __syncthreads();
    // exclusive scan lcnt -> lbase (Hillis-Steele, lcnt preserved)
    u32 v = lcnt[t];
    sc[t] = v;
    __syncthreads();
#pragma unroll
    for (int st = 1; st < 256; st <<= 1) {
        u32 u = (t >= st) ? sc[t - st] : 0;
        __syncthreads();
        sc[t] += u;
        __syncthreads();
    }
    lbase[t] = sc[t] - v;
    gbase[t] = atomicAdd(&bcur[t], v);             // global base per bucket
    __syncthreads();
#pragma unroll
    for (int j = 0; j < 16; ++j) if (vd[j]) {
        u32 idx = lbase[bk[j]] + rk[j];
        lpair[idx] = pr[j];
        lbkt[idx]  = bk[j];
    }
    __syncthreads();
    int nloc = lbase[255] + lcnt[255];             // total valid this block
    for (int i = t; i < nloc; i += 256) {
        u32 b = lbkt[i];
        u32 g = gbase[b] + (i - lbase[b]);
        u32 p = lpair[i];
        if (g < BCAP) stg[(size_t)b * BCAP + g] = p;
        else { u32 o = atomicAdd(ovf, 1u); if (o < 4096) stg2[o] = p; }
    }
}

// ---- scan stage A ----
__global__ __launch_bounds__(SCAN_B) void k_scan_a(const int* __restrict__ deg,
                                                   int* __restrict__ off,
                                                   int* __restrict__ bsum) {
    __shared__ int sh[SCAN_B];
    int t = threadIdx.x, i = blockIdx.x * SCAN_B + t;
    int v = (i < NN) ? deg[i] : 0;
    sh[t] = v;
    __syncthreads();
#pragma unroll
    for (int s = 1; s < SCAN_B; s <<= 1) {
        int u = (t >= s) ? sh[t - s] : 0;
        __syncthreads();
        sh[t] += u;
        __syncthreads();
    }
    if (i < NN) off[i] = sh[t] - v;
    if (t == SCAN_B - 1) bsum[blockIdx.x] = sh[t];
}

// ---- scan stage B ----
__global__ __launch_bounds__(SCAN_B) void k_scan_b(int* __restrict__ bsum,
                                                   int* __restrict__ off) {
    __shared__ int sh[SCAN_B];
    int t = threadIdx.x;
    int v = (t < NBLK) ? bsum[t] : 0;
    sh[t] = v;
    __syncthreads();
#pragma unroll
    for (int s = 1; s < SCAN_B; s <<= 1) {
        int u = (t >= s) ? sh[t - s] : 0;
        __syncthreads();
        sh[t] += u;
        __syncthreads();
    }
    if (t < NBLK) bsum[t] = sh[t] - v;
    if (t == 0) off[NN] = ET;
}

// ---- scan stage C ----
__global__ __launch_bounds__(SCAN_B) void k_scan_c(int* __restrict__ off,
                                                   const int* __restrict__ bsum) {
    int i = blockIdx.x * SCAN_B + threadIdx.x;
    if (i >= NN) return;
    off[i] += bsum[blockIdx.x];
}

// ---- pass B: one block per bucket; LDS cursors from off; coalesced csr write ----
__global__ __launch_bounds__(256) void k_place(
        const int* __restrict__ off, const u32* __restrict__ bcur,
        const u32* __restrict__ stg, const u32* __restrict__ stg2,
        const u32* __restrict__ ovf, u16* __restrict__ csr16) {
    __shared__ u32 lcur[256];
    __shared__ u16 lcsr[BCAP];
    int b = blockIdx.x, t = threadIdx.x;
    int n0 = b << 8;
    int n1 = min(n0 + 256, NN);
    int S0 = off[n0];
    int span = off[n1] - S0;
    if (n0 + t < n1) lcur[t] = (u32)(off[n0 + t] - S0);
    __syncthreads();
    u32 cnt = bcur[b];
    u32 cmain = min(cnt, (u32)BCAP);
    bool direct = (span > BCAP);                   // pathological only
    for (u32 i = t; i < cmain; i += 256) {
        u32 p = stg[(size_t)b * BCAP + i];
        u32 nrel = (p >> 16) & 255u;
        u32 r = atomicAdd(&lcur[nrel], 1u);
        if (direct) csr16[S0 + r] = (u16)(p & 0xFFFFu);
        else        lcsr[r] = (u16)(p & 0xFFFFu);
    }
    if (cnt > cmain) {                             // staged overflow (≈never)
        u32 no = min(*ovf, 4096u);
        for (u32 i = t; i < no; i += 256) {
            u32 p = stg2[i];
            if ((p >> 24) == (u32)b) {
                u32 nrel = (p >> 16) & 255u;
                u32 r = atomicAdd(&lcur[nrel], 1u);
                if (direct) csr16[S0 + r] = (u16)(p & 0xFFFFu);
                else        lcsr[r] = (u16)(p & 0xFFFFu);
            }
        }
    }
    __syncthreads();
    if (!direct)
        for (int i = t; i < span; i += 256) csr16[S0 + i] = lcsr[i];
}

// ---- layer1 node transform: 4 nodes per block ----
__global__ __launch_bounds__(512) void k_node1(
        const float* __restrict__ x, const float* __restrict__ W1,
        const float* __restrict__ as1, const float* __restrict__ ad1,
        u16* __restrict__ hbf, float* __restrict__ asrc, float* __restrict__ adst) {
    int t = threadIdx.x;
    int n = blockIdx.x * 4 + (t >> 7);
    int c = t & 127;
    if (n >= NN) return;
    float x0 = x[2 * n], x1 = x[2 * n + 1];
    float hv = fmaf(x0, W1[c], x1 * W1[128 + c]);
    hbf[(size_t)n * 128 + c] = f2bf(hv);
    float ps = hv * as1[c], pd = hv * ad1[c];
#pragma unroll
    for (int m = 16; m >= 1; m >>= 1) {
        ps += __shfl_xor(ps, m);
        pd += __shfl_xor(pd, m);
    }
    if ((c & 31) == 0) {
        int hd = c >> 5;
        asrc[n * 4 + hd] = ps;
        adst[n * 4 + hd] = pd;
    }
}

// ---- layer1 gather-aggregate: one wave per node, 2 nodes/block, heads=4 ----
__global__ __launch_bounds__(128) void k_agg1w(
        const int* __restrict__ off, const u16* __restrict__ csr,
        const float* __restrict__ asrc, const float* __restrict__ adst,
        const u16* __restrict__ hbf, const float* __restrict__ b1,
        u32* __restrict__ x2bf) {
    __shared__ float2 pair[2][4][DCAP];    // [wave][head][edge] {ex, bytes(src<<8)}
    int t = threadIdx.x;
    int wv = t >> 6, l = t & 63;
    int n = blockIdx.x * 2 + wv;
    if (n >= NN) return;                   // whole wave exits; no barriers anywhere
    int hd = l >> 4, li = l & 15;          // head, lane-in-head
    int e0 = off[n], deg = off[n + 1] - e0;
    float ad = adst[n * 4 + hd];
    float a0 = 0.f, a1 = 0.f, inv;
    const char* hc = (const char*)hbf + 4 * l;   // this thread's 2-channel base

    if (deg <= DCAP) {
        float mymax = -1e30f;
        for (int e = li; e < deg; e += 16) {
            int s = csr[e0 + e];
            float al = lrelu(asrc[s * 4 + hd] + ad);
            pair[wv][hd][e] = make_float2(al, __int_as_float(s << 8));
            mymax = fmaxf(mymax, al);
        }
#pragma unroll
        for (int m = 8; m >= 1; m >>= 1) mymax = fmaxf(mymax, __shfl_xor(mymax, m));
        float myden = 0.f;
        for (int e = li; e < deg; e += 16) {
            float ex = __expf(pair[wv][hd][e].x - mymax);
            pair[wv][hd][e].x = ex;
            myden += ex;
        }
#pragma unroll
        for (int m = 8; m >= 1; m >>= 1) myden += __shfl_xor(myden, m);
        inv = 1.f / (myden + 1e-16f);
#pragma unroll 4
        for (int e = 0; e < deg; ++e) {
            float2 p = pair[wv][hd][e];
            u32 hw = *(const u32*)(hc + (size_t)(u32)__float_as_int(p.y));
            a0 = fmaf(p.x, __uint_as_float(hw << 16), a0);
            a1 = fmaf(p.x, __uint_as_float(hw & 0xFFFF0000u), a1);
        }
    } else {
        // fallback (degree overflow; correctness guarantee)
        float amax = -1e30f;
        for (int e = e0; e < e0 + deg; ++e)
            amax = fmaxf(amax, lrelu(asrc[csr[e] * 4 + hd] + ad));
        float den = 0.f;
        for (int e = e0; e < e0 + deg; ++e) {
            int s = csr[e];
            float ex = __expf(lrelu(asrc[s * 4 + hd] + ad) - amax);
            den += ex;
            u32 hw = *(const u32*)(hc + (size_t)((u32)s << 8));
            a0 = fmaf(ex, __uint_as_float(hw << 16), a0);
            a1 = fmaf(ex, __uint_as_float(hw & 0xFFFF0000u), a1);
        }
        inv = 1.f / (den + 1e-16f);
    }
    float2 bb = *(const float2*)(b1 + 2 * l);
    float v0 = fmaxf(fmaf(a0, inv, bb.x), 0.f);
    float v1 = fmaxf(fmaf(a1, inv, bb.y), 0.f);
    x2bf[(size_t)n * 64 + l] = (u32)f2bf(v0) | ((u32)f2bf(v1) << 16);
}

// ---- layer2 node transform via MFMA bf16 (as R9/R10) ----
__global__ __launch_bounds__(256) void k_node2m(
        const u32* __restrict__ x2bf,
        const u16* __restrict__ w2t, const float* __restrict__ as2,
        const float* __restrict__ ad2, u16* __restrict__ h2bf,
        float* __restrict__ asrc, float* __restrict__ adst) {
    __shared__ u16 xt[64 * 128];    // 16 KB, x-tile bf16, swizzled rows
    __shared__ u16 wt[128 * 128];   // 32 KB, W2T [col][k] bf16, swizzled rows
    int t = threadIdx.x;
    int n0 = blockIdx.x * 64;

#pragma unroll
    for (int i = 0; i < 4; ++i) {
        int c8 = t + i * 256;
        int r = c8 >> 4, k8 = c8 & 15;
        int n = n0 + r;
        uint4 v = make_uint4(0, 0, 0, 0);
        if (n < NN) v = *(const uint4*)(x2bf + (size_t)n * 64 + k8 * 4);
        int offb = r * 256 + ((k8 * 16) ^ ((r & 7) << 4));
        *(uint4*)((char*)xt + offb) = v;
    }
#pragma unroll
    for (int i = 0; i < 8; ++i) {
        int c8 = t + i * 256;
        int row = c8 >> 4, k8 = c8 & 15;
        uint4 wv = *(const uint4*)(w2t + row * 128 + k8 * 8);
        int offb = row * 256 + ((k8 * 16) ^ ((row & 7) << 4));
        *(uint4*)((char*)wt + offb) = wv;
    }
    __syncthreads();

    int l = t & 63, w = t >> 6;
    int lr = l & 15, lg = l >> 4;

    bf16x8 afr[4];
    int ar = w * 16 + lr;
#pragma unroll
    for (int kc = 0; kc < 4; ++kc) {
        int kbyte = kc * 64 + lg * 16;
        afr[kc] = *(const bf16x8*)((char*)xt + ar * 256 + (kbyte ^ ((ar & 7) << 4)));
    }

    f32x4 acc[8];
#pragma unroll
    for (int ct = 0; ct < 8; ++ct) {
        f32x4 c = {0.f, 0.f, 0.f, 0.f};
        int br = ct * 16 + lr;
#pragma unroll
        for (int kc = 0; kc < 4; ++kc) {
            int kbyte = kc * 64 + lg * 16;
            bf16x8 b = *(const bf16x8*)((char*)wt + br * 256 + (kbyte ^ ((br & 7) << 4)));
            c = __builtin_amdgcn_mfma_f32_16x16x32_bf16(afr[kc], b, c, 0, 0, 0);
        }
        acc[ct] = c;
    }

    float asv[8], adv[8];
#pragma unroll
    for (int ct = 0; ct < 8; ++ct) {
        asv[ct] = as2[ct * 16 + lr];
        adv[ct] = ad2[ct * 16 + lr];
    }
#pragma unroll
    for (int reg = 0; reg < 4; ++reg) {
        float ps = 0.f, pd = 0.f;
#pragma unroll
        for (int ct = 0; ct < 8; ++ct) {
            ps = fmaf(acc[ct][reg], asv[ct], ps);
            pd = fmaf(acc[ct][reg], adv[ct], pd);
        }
#pragma unroll
        for (int m = 8; m >= 1; m >>= 1) {
            ps += __shfl_xor(ps, m);
            pd += __shfl_xor(pd, m);
        }
        int n = n0 + w * 16 + lg * 4 + reg;
        if (n < NN) {
#pragma unroll
            for (int ct = 0; ct < 8; ++ct)
                h2bf[(size_t)n * 128 + ct * 16 + lr] = f2bf(acc[ct][reg]);
            if (lr == 0) { asrc[n] = ps; adst[n] = pd; }
        }
    }
}

// ---- layer2 gather-aggregate: one wave per node, 2 nodes/block, heads=1 ----
__global__ __launch_bounds__(128) void k_agg2w(
        const int* __restrict__ off, const u16* __restrict__ csr,
        const float* __restrict__ asrc, const float* __restrict__ adst,
        const u16* __restrict__ hbf, float* __restrict__ ob) {
    __shared__ float2 pair[2][DCAP];
    int t = threadIdx.x;
    int wv = t >> 6, l = t & 63;
    int n = blockIdx.x * 2 + wv;
    if (n >= NN) return;
    int e0 = off[n], deg = off[n + 1] - e0;
    float ad = adst[n];
    float a0 = 0.f, a1 = 0.f, inv;
    const char* hc = (const char*)hbf + 4 * l;

    if (deg <= DCAP) {
        float mymax = -1e30f;
        for (int e = l; e < deg; e += 64) {
            int s = csr[e0 + e];
            float al = lrelu(asrc[s] + ad);
            pair[wv][e] = make_float2(al, __int_as_float(s << 8));
            mymax = fmaxf(mymax, al);
        }
#pragma unroll
        for (int m = 32; m >= 1; m >>= 1) mymax = fmaxf(mymax, __shfl_xor(mymax, m));
        float myden = 0.f;
        for (int e = l; e < deg; e += 64) {
            float ex = __expf(pair[wv][e].x - mymax);
            pair[wv][e].x = ex;
            myden += ex;
        }
#pragma unroll
        for (int m = 32; m >= 1; m >>= 1) myden += __shfl_xor(myden, m);
        inv = 1.f / (myden + 1e-16f);
#pragma unroll 4
        for (int e = 0; e < deg; ++e) {
            float2 p = pair[wv][e];
            u32 hw = *(const u32*)(hc + (size_t)(u32)__float_as_int(p.y));
            a0 = fmaf(p.x, __uint_as_float(hw << 16), a0);
            a1 = fmaf(p.x, __uint_as_float(hw & 0xFFFF0000u), a1);
        }
    } else {
        float amax = -1e30f;
        for (int e = e0; e < e0 + deg; ++e)
            amax = fmaxf(amax, lrelu(asrc[csr[e]] + ad));
        float den = 0.f;
        for (int e = e0; e < e0 + deg; ++e) {
            int s = csr[e];
            float ex = __expf(lrelu(asrc[s] + ad) - amax);
            den += ex;
            u32 hw = *(const u32*)(hc + (size_t)((u32)s << 8));
            a0 = fmaf(ex, __uint_as_float(hw << 16), a0);
            a1 = fmaf(ex, __uint_as_float(hw & 0xFFFF0000u), a1);
        }
        inv = 1.f / (den + 1e-16f);
    }
    *(float2*)(ob + (size_t)n * 128 + 2 * l) = make_float2(a0 * inv, a1 * inv);
}

// ---- final: mean over nodes; 1024 blocks x 256 thr (2 rows/iter/block),
//      LDS pre-reduce then one atomic per channel per block. d_out pre-set b2.
__global__ __launch_bounds__(256) void k_final(const float* __restrict__ ob,
                                               float* __restrict__ out) {
    __shared__ float red[256];
    int t = threadIdx.x;
    int c = t & 127, rp = t >> 7;
    float acc = 0.f;
    for (int n = blockIdx.x * 2 + rp; n < NN; n += 2048)
        acc += ob[(size_t)n * 128 + c];
    red[t] = acc;
    __syncthreads();
    if (t < 128) atomicAdd(out + t, (red[t] + red[t + 128]) * (1.0f / NN));
}

extern "C" void kernel_launch(void* const* d_in, const int* in_sizes, int n_in,
                              void* d_out, int out_size, void* d_ws, size_t ws_size,
                              hipStream_t stream) {
    const float* x   = (const float*)d_in[0];
    const int*   ei  = (const int*)d_in[1];
    const float* W1  = (const float*)d_in[2];
    const float* as1 = (const float*)d_in[3];
    const float* ad1 = (const float*)d_in[4];
    const float* b1  = (const float*)d_in[5];
    const float* W2  = (const float*)d_in[6];
    const float* as2 = (const float*)d_in[7];
    const float* ad2 = (const float*)d_in[8];
    const float* b2  = (const float*)d_in[9];
    float* out = (float*)d_out;

    char* ws    = (char*)d_ws;
    u16*  hbf   = (u16*)ws;                              // NN*128 bf16 (h1, then h2)
    u32*  x2bf  = (u32*)(hbf + (size_t)NN * 128);        // NN*64 packed bf16 x2
    u32*  stg   = x2bf;                                  // ALIAS: stg dead before x2bf written
    float* ob   = (float*)(x2bf + (size_t)NN * 64);      // NN*128 f32 (out2)
    float* asr1 = ob + (size_t)NN * 128;                 // NN*4
    float* adt1 = asr1 + NN * 4;                         // NN*4
    float* asr2 = adt1 + NN * 4;                         // NN
    float* adt2 = asr2 + NN;                             // NN
    int* deg    = (int*)(adt2 + NN);                     // NN
    int* off    = deg + NN;                              // NN+1
    int* bsum   = off + NN + 1;                          // NBLK
    u16* w2t    = (u16*)(bsum + NBLK);                   // 128*128 bf16
    u32* bcur   = (u32*)(w2t + 128 * 128);               // 256
    u32* ovf    = bcur + 256;                            // 1 (+pad)
    u32* stg2   = ovf + 4;                               // 4096 overflow pairs
    u16* csr16  = (u16*)(stg2 + 4096);                   // ET u16

    // CSR build: fused deg+partition, scan, place
    k_init<<<(NN + 255) / 256, 256, 0, stream>>>(deg, b2, out, W2, w2t, bcur, ovf);
    k_part<<<NWGP, 256, 0, stream>>>(ei, deg, bcur, stg, stg2, ovf);
    k_scan_a<<<NBLK, SCAN_B, 0, stream>>>(deg, off, bsum);
    k_scan_b<<<1, SCAN_B, 0, stream>>>(bsum, off);
    k_scan_c<<<NBLK, SCAN_B, 0, stream>>>(off, bsum);
    k_place<<<NB, 256, 0, stream>>>(off, bcur, stg, stg2, ovf, csr16);

    // layer 1
    k_node1<<<(NN + 3) / 4, 512, 0, stream>>>(x, W1, as1, ad1, hbf, asr1, adt1);
    k_agg1w<<<(NN + 1) / 2, 128, 0, stream>>>(off, csr16, asr1, adt1, hbf, b1, x2bf);

    // layer 2: MFMA GEMM reads x2bf, writes hbf(h2 bf16) + attn dots
    k_node2m<<<(NN + 63) / 64, 256, 0, stream>>>(x2bf, w2t, as2, ad2, hbf, asr2, adt2);
    k_agg2w<<<(NN + 1) / 2, 128, 0, stream>>>(off, csr16, asr2, adt2, hbf, ob);

    // mean pool (+b2 already in out)
    k_final<<<1024, 256, 0, stream>>>(ob, out);
}

// Round 14
// 194.600 us; speedup vs baseline: 1.8308x; 1.0637x over previous
//
#include <hip/hip_runtime.h>

#define NN 50000
#define NE 800000
#define ET (NE + NN)   // 850000 edges incl. self-loops
#define SCAN_B 256
#define NBLK ((NN + SCAN_B - 1) / SCAN_B)   // 196
#define EPW 4096       // edges per k_part workgroup
#define NWGP ((ET + EPW - 1) / EPW)         // 208
#define NB 196         // buckets = dst>>8
#define BCAP 6144      // staging capacity per bucket (mean 4337, sd ~66)

typedef unsigned short u16;
typedef unsigned int u32;
typedef unsigned char u8;

__device__ __forceinline__ float lrelu(float a) { return a > 0.f ? a : 0.2f * a; }

// ---- init: zero deg/w/z/bcur/ovf; precompute A,D (2x4 attn dots of W1) and
//      vs,vd (W2 @ as2 / ad2, 128 each) ----
__global__ void k_init(int* __restrict__ deg, float* __restrict__ w,
                       u32* __restrict__ bcur, u32* __restrict__ ovf,
                       float* __restrict__ z,
                       const float* __restrict__ W1, const float* __restrict__ as1,
                       const float* __restrict__ ad1, const float* __restrict__ W2,
                       const float* __restrict__ as2, const float* __restrict__ ad2,
                       float* __restrict__ AD, float* __restrict__ vs,
                       float* __restrict__ vd) {
    int i = blockIdx.x * blockDim.x + threadIdx.x;
    if (i < NN)  { deg[i] = 0; w[i] = 0.f; }
    if (i < 256) bcur[i] = 0;
    if (i == 0)  *ovf = 0;
    if (i < 128) {
        z[i] = 0.f;
        float a = 0.f, d = 0.f;
        for (int c = 0; c < 128; ++c) {
            float wv = W2[i * 128 + c];
            a = fmaf(wv, as2[c], a);
            d = fmaf(wv, ad2[c], d);
        }
        vs[i] = a; vd[i] = d;
    }
    if (i >= 128 && i < 144) {
        int q = i - 128, isD = q >> 3, j = (q >> 2) & 1, hd = q & 3;
        const float* att = isD ? ad1 : as1;
        float acc = 0.f;
        for (int ch = 0; ch < 32; ++ch)
            acc = fmaf(W1[j * 128 + hd * 32 + ch], att[hd * 32 + ch], acc);
        AD[isD * 8 + j * 4 + hd] = acc;   // A0|A1|D0|D1, each [4]
    }
}

// ---- pass A: fused degree count + bucket partition (LDS counting sort) ----
__global__ __launch_bounds__(256) void k_part(
        const int* __restrict__ ei, int* __restrict__ deg,
        u32* __restrict__ bcur, u32* __restrict__ stg,
        u32* __restrict__ stg2, u32* __restrict__ ovf) {
    __shared__ u32 lcnt[256], sc[256], lbase[256], gbase[256];
    __shared__ u32 lpair[EPW];
    __shared__ u8  lbkt[EPW];
    int t = threadIdx.x;
    int e0 = blockIdx.x * EPW;
    lcnt[t] = 0;
    __syncthreads();

    u32 pr[16]; u16 rk[16]; u8 bk[16]; bool vd_[16];
#pragma unroll
    for (int j = 0; j < 16; ++j) {
        int e = e0 + j * 256 + t;
        vd_[j] = (e < ET);
        if (vd_[j]) {
            int s, d;
            if (e < NE) { s = ei[e]; d = ei[NE + e]; } else { s = d = e - NE; }
            atomicAdd(deg + d, 1);
            pr[j] = ((u32)d << 16) | (u32)s;
            int b = d >> 8;
            bk[j] = (u8)b;
            rk[j] = (u16)atomicAdd(&lcnt[b], 1u);
        }
    }
    __syncthreads();
    u32 v = lcnt[t];
    sc[t] = v;
    __syncthreads();
#pragma unroll
    for (int st = 1; st < 256; st <<= 1) {
        u32 u = (t >= st) ? sc[t - st] : 0;
        __syncthreads();
        sc[t] += u;
        __syncthreads();
    }
    lbase[t] = sc[t] - v;
    gbase[t] = atomicAdd(&bcur[t], v);
    __syncthreads();
#pragma unroll
    for (int j = 0; j < 16; ++j) if (vd_[j]) {
        u32 idx = lbase[bk[j]] + rk[j];
        lpair[idx] = pr[j];
        lbkt[idx]  = bk[j];
    }
    __syncthreads();
    int nloc = lbase[255] + lcnt[255];
    for (int i = t; i < nloc; i += 256) {
        u32 b = lbkt[i];
        u32 g = gbase[b] + (i - lbase[b]);
        u32 p = lpair[i];
        if (g < BCAP) stg[(size_t)b * BCAP + g] = p;
        else { u32 o = atomicAdd(ovf, 1u); if (o < 4096) stg2[o] = p; }
    }
}

// ---- scan stage A ----
__global__ __launch_bounds__(SCAN_B) void k_scan_a(const int* __restrict__ deg,
                                                   int* __restrict__ off,
                                                   int* __restrict__ bsum) {
    __shared__ int sh[SCAN_B];
    int t = threadIdx.x, i = blockIdx.x * SCAN_B + t;
    int v = (i < NN) ? deg[i] : 0;
    sh[t] = v;
    __syncthreads();
#pragma unroll
    for (int s = 1; s < SCAN_B; s <<= 1) {
        int u = (t >= s) ? sh[t - s] : 0;
        __syncthreads();
        sh[t] += u;
        __syncthreads();
    }
    if (i < NN) off[i] = sh[t] - v;
    if (t == SCAN_B - 1) bsum[blockIdx.x] = sh[t];
}

// ---- scan stage B ----
__global__ __launch_bounds__(SCAN_B) void k_scan_b(int* __restrict__ bsum,
                                                   int* __restrict__ off) {
    __shared__ int sh[SCAN_B];
    int t = threadIdx.x;
    int v = (t < NBLK) ? bsum[t] : 0;
    sh[t] = v;
    __syncthreads();
#pragma unroll
    for (int s = 1; s < SCAN_B; s <<= 1) {
        int u = (t >= s) ? sh[t - s] : 0;
        __syncthreads();
        sh[t] += u;
        __syncthreads();
    }
    if (t < NBLK) bsum[t] = sh[t] - v;
    if (t == 0) off[NN] = ET;
}

// ---- scan stage C ----
__global__ __launch_bounds__(SCAN_B) void k_scan_c(int* __restrict__ off,
                                                   const int* __restrict__ bsum) {
    int i = blockIdx.x * SCAN_B + threadIdx.x;
    if (i >= NN) return;
    off[i] += bsum[blockIdx.x];
}

// ---- pass B: one block per bucket; LDS cursors; coalesced csr write ----
__global__ __launch_bounds__(256) void k_place(
        const int* __restrict__ off, const u32* __restrict__ bcur,
        const u32* __restrict__ stg, const u32* __restrict__ stg2,
        const u32* __restrict__ ovf, u16* __restrict__ csr16) {
    __shared__ u32 lcur[256];
    __shared__ u16 lcsr[BCAP];
    int b = blockIdx.x, t = threadIdx.x;
    int n0 = b << 8;
    int n1 = min(n0 + 256, NN);
    int S0 = off[n0];
    int span = off[n1] - S0;
    if (n0 + t < n1) lcur[t] = (u32)(off[n0 + t] - S0);
    __syncthreads();
    u32 cnt = bcur[b];
    u32 cmain = min(cnt, (u32)BCAP);
    bool direct = (span > BCAP);
    for (u32 i = t; i < cmain; i += 256) {
        u32 p = stg[(size_t)b * BCAP + i];
        u32 nrel = (p >> 16) & 255u;
        u32 r = atomicAdd(&lcur[nrel], 1u);
        if (direct) csr16[S0 + r] = (u16)(p & 0xFFFFu);
        else        lcsr[r] = (u16)(p & 0xFFFFu);
    }
    if (cnt > cmain) {
        u32 no = min(*ovf, 4096u);
        for (u32 i = t; i < no; i += 256) {
            u32 p = stg2[i];
            if ((p >> 24) == (u32)b) {
                u32 nrel = (p >> 16) & 255u;
                u32 r = atomicAdd(&lcur[nrel], 1u);
                if (direct) csr16[S0 + r] = (u16)(p & 0xFFFFu);
                else        lcsr[r] = (u16)(p & 0xFFFFu);
            }
        }
    }
    __syncthreads();
    if (!direct)
        for (int i = t; i < span; i += 256) csr16[S0 + i] = lcsr[i];
}

// ---- layer1 aggregate via rank-2 reconstruction, fused with bias/relu and
//      layer-2 attention dots. One wave per node; 16-lane group per head.
//      Gathers only x (8B/edge, L2-resident). No LDS, no degree cap. ----
__global__ __launch_bounds__(128) void k_agg1x(
        const int* __restrict__ off, const u16* __restrict__ csr,
        const float* __restrict__ x, const float* __restrict__ AD,
        const float* __restrict__ W1, const float* __restrict__ b1,
        const float* __restrict__ vs, const float* __restrict__ vd,
        float* __restrict__ x2, float* __restrict__ asrc2,
        float* __restrict__ adst2) {
    int t = threadIdx.x;
    int wv = t >> 6, l = t & 63;
    int n = blockIdx.x * 2 + wv;
    if (n >= NN) return;
    int hd = l >> 4, li = l & 15;
    int e0 = off[n], deg = off[n + 1] - e0;
    float2 xd = *(const float2*)(x + 2 * n);
    float A0 = AD[hd], A1 = AD[4 + hd], D0 = AD[8 + hd], D1 = AD[12 + hd];
    float adn = fmaf(D0, xd.x, D1 * xd.y);

    float mymax = -1e30f;
    for (int e = li; e < deg; e += 16) {
        int s = csr[e0 + e];
        float2 xv = *(const float2*)(x + 2 * s);
        float al = lrelu(fmaf(A0, xv.x, A1 * xv.y) + adn);
        mymax = fmaxf(mymax, al);
    }
#pragma unroll
    for (int m = 8; m >= 1; m >>= 1) mymax = fmaxf(mymax, __shfl_xor(mymax, m));

    float den = 0.f, S0 = 0.f, S1 = 0.f;
    for (int e = li; e < deg; e += 16) {
        int s = csr[e0 + e];
        float2 xv = *(const float2*)(x + 2 * s);
        float al = lrelu(fmaf(A0, xv.x, A1 * xv.y) + adn);
        float ex = __expf(al - mymax);
        den += ex;
        S0 = fmaf(ex, xv.x, S0);
        S1 = fmaf(ex, xv.y, S1);
    }
#pragma unroll
    for (int m = 8; m >= 1; m >>= 1) {
        den += __shfl_xor(den, m);
        S0  += __shfl_xor(S0, m);
        S1  += __shfl_xor(S1, m);
    }
    float inv = 1.f / (den + 1e-16f);

    // channels c0=2l, c0+1 belong to head l>>4 == hd
    int c0 = 2 * l;
    float o0 = (S0 * W1[c0]     + S1 * W1[128 + c0])     * inv;
    float o1 = (S0 * W1[c0 + 1] + S1 * W1[128 + c0 + 1]) * inv;
    float v0 = fmaxf(o0 + b1[c0], 0.f);
    float v1 = fmaxf(o1 + b1[c0 + 1], 0.f);
    *(float2*)(x2 + (size_t)n * 128 + c0) = make_float2(v0, v1);

    // fused layer-2 attention dots: asrc2 = x2·vs, adst2 = x2·vd
    float ps = fmaf(v0, vs[c0], v1 * vs[c0 + 1]);
    float pd = fmaf(v0, vd[c0], v1 * vd[c0 + 1]);
#pragma unroll
    for (int m = 32; m >= 1; m >>= 1) {
        ps += __shfl_xor(ps, m);
        pd += __shfl_xor(pd, m);
    }
    if (l == 0) { asrc2[n] = ps; adst2[n] = pd; }
}

// ---- layer2 softmax on scalars: per dst amax/den, per edge coef -> w[src].
//      16 lanes per node, 8 nodes per 128-thr block. All data L2-resident. ----
__global__ __launch_bounds__(128) void k_sm2(
        const int* __restrict__ off, const u16* __restrict__ csr,
        const float* __restrict__ asrc2, const float* __restrict__ adst2,
        float* __restrict__ w) {
    int t = threadIdx.x;
    int g = t >> 4, li = t & 15;
    int n = blockIdx.x * 8 + g;
    if (n >= NN) return;
    int e0 = off[n], deg = off[n + 1] - e0;
    float adn = adst2[n];

    float mymax = -1e30f;
    for (int e = li; e < deg; e += 16)
        mymax = fmaxf(mymax, lrelu(asrc2[csr[e0 + e]] + adn));
#pragma unroll
    for (int m = 8; m >= 1; m >>= 1) mymax = fmaxf(mymax, __shfl_xor(mymax, m));

    float den = 0.f;
    for (int e = li; e < deg; e += 16)
        den += __expf(lrelu(asrc2[csr[e0 + e]] + adn) - mymax);
#pragma unroll
    for (int m = 8; m >= 1; m >>= 1) den += __shfl_xor(den, m);
    float inv = 1.f / (den + 1e-16f);

    for (int e = li; e < deg; e += 16) {
        int s = csr[e0 + e];
        float coef = __expf(lrelu(asrc2[s] + adn) - mymax) * inv;
        atomicAdd(w + s, coef);
    }
}

// ---- weighted column sum: z = sum_n w[n] * x2[n] ----
__global__ __launch_bounds__(256) void k_wsum(const float* __restrict__ w,
                                              const float* __restrict__ x2,
                                              float* __restrict__ z) {
    __shared__ float red[256];
    int t = threadIdx.x, c = t & 127, rp = t >> 7;
    float acc = 0.f;
    for (int n = blockIdx.x * 2 + rp; n < NN; n += 2048)
        acc = fmaf(w[n], x2[(size_t)n * 128 + c], acc);
    red[t] = acc;
    __syncthreads();
    if (t < 128) atomicAdd(z + t, red[t] + red[t + 128]);
}

// ---- final: d_out = b2 + (z @ W2) / N  (128x128 GEMV, one block) ----
__global__ __launch_bounds__(128) void k_out(const float* __restrict__ z,
                                             const float* __restrict__ W2,
                                             const float* __restrict__ b2,
                                             float* __restrict__ out) {
    int c = threadIdx.x;
    float acc = 0.f;
    for (int k = 0; k < 128; ++k)
        acc = fmaf(z[k], W2[k * 128 + c], acc);
    out[c] = b2[c] + acc * (1.0f / NN);
}

extern "C" void kernel_launch(void* const* d_in, const int* in_sizes, int n_in,
                              void* d_out, int out_size, void* d_ws, size_t ws_size,
                              hipStream_t stream) {
    const float* x   = (const float*)d_in[0];
    const int*   ei  = (const int*)d_in[1];
    const float* W1  = (const float*)d_in[2];
    const float* as1 = (const float*)d_in[3];
    const float* ad1 = (const float*)d_in[4];
    const float* b1  = (const float*)d_in[5];
    const float* W2  = (const float*)d_in[6];
    const float* as2 = (const float*)d_in[7];
    const float* ad2 = (const float*)d_in[8];
    const float* b2  = (const float*)d_in[9];
    float* out = (float*)d_out;

    char* ws     = (char*)d_ws;
    float* x2    = (float*)ws;                           // NN*128 f32
    u32*  stg    = (u32*)x2;                             // ALIAS: dead before x2 written
    float* w     = x2 + (size_t)NN * 128;                // NN
    float* asrc2 = w + NN;                               // NN
    float* adst2 = asrc2 + NN;                           // NN
    int* deg     = (int*)(adst2 + NN);                   // NN
    int* off     = deg + NN;                             // NN+1
    int* bsum    = off + NN + 1;                         // NBLK
    u32* bcur    = (u32*)(bsum + NBLK);                  // 256
    u32* ovf     = bcur + 256;                           // 4
    u32* stg2    = ovf + 4;                              // 4096
    u16* csr16   = (u16*)(stg2 + 4096);                  // ET u16
    float* AD    = (float*)(csr16 + ET);                 // 16
    float* vs    = AD + 16;                              // 128
    float* vd    = vs + 128;                             // 128
    float* z     = vd + 128;                             // 128

    // init + precompute attention projections
    k_init<<<(NN + 255) / 256, 256, 0, stream>>>(deg, w, bcur, ovf, z,
                                                 W1, as1, ad1, W2, as2, ad2,
                                                 AD, vs, vd);
    // CSR build
    k_part<<<NWGP, 256, 0, stream>>>(ei, deg, bcur, stg, stg2, ovf);
    k_scan_a<<<NBLK, SCAN_B, 0, stream>>>(deg, off, bsum);
    k_scan_b<<<1, SCAN_B, 0, stream>>>(bsum, off);
    k_scan_c<<<NBLK, SCAN_B, 0, stream>>>(off, bsum);
    k_place<<<NB, 256, 0, stream>>>(off, bcur, stg, stg2, ovf, csr16);

    // layer 1 (rank-2) + fused layer-2 dots
    k_agg1x<<<(NN + 1) / 2, 128, 0, stream>>>(off, csr16, x, AD, W1, b1,
                                              vs, vd, x2, asrc2, adst2);
    // layer 2 softmax weights, weighted sum, output GEMV
    k_sm2<<<(NN + 7) / 8, 128, 0, stream>>>(off, csr16, asrc2, adst2, w);
    k_wsum<<<1024, 256, 0, stream>>>(w, x2, z);
    k_out<<<1, 128, 0, stream>>>(z, W2, b2, out);
}

// Round 15
// 183.075 us; speedup vs baseline: 1.9460x; 1.0630x over previous
//
#include <hip/hip_runtime.h>

#define NN 50000
#define NE 800000
#define ET (NE + NN)   // 850000 edges incl. self-loops
#define EPW 4096       // edges per k_part workgroup
#define NWGP ((ET + EPW - 1) / EPW)         // 208
#define NB 196         // buckets = dst>>8 (aligned with 256-node scan tiles)
#define BCAP 6144      // staging capacity per bucket (mean 4337, sd ~66)
#define RC 8           // register-cache slots per lane (fast path deg <= 128)

typedef unsigned short u16;
typedef unsigned int u32;
typedef unsigned char u8;

__device__ __forceinline__ float lrelu(float a) { return a > 0.f ? a : 0.2f * a; }

// ---- init: zero deg/w/z/bcur/ovf; precompute A,D (2x4 attn dots of W1) and
//      vs,vd (W2 @ as2 / ad2, 128 each) ----
__global__ void k_init(int* __restrict__ deg, float* __restrict__ w,
                       u32* __restrict__ bcur, u32* __restrict__ ovf,
                       float* __restrict__ z,
                       const float* __restrict__ W1, const float* __restrict__ as1,
                       const float* __restrict__ ad1, const float* __restrict__ W2,
                       const float* __restrict__ as2, const float* __restrict__ ad2,
                       float* __restrict__ AD, float* __restrict__ vs,
                       float* __restrict__ vd) {
    int i = blockIdx.x * blockDim.x + threadIdx.x;
    if (i < NN)  { deg[i] = 0; w[i] = 0.f; }
    if (i < 256) bcur[i] = 0;
    if (i == 0)  *ovf = 0;
    if (i < 128) {
        z[i] = 0.f;
        float a = 0.f, d = 0.f;
        for (int c = 0; c < 128; ++c) {
            float wv = W2[i * 128 + c];
            a = fmaf(wv, as2[c], a);
            d = fmaf(wv, ad2[c], d);
        }
        vs[i] = a; vd[i] = d;
    }
    if (i >= 128 && i < 144) {
        int q = i - 128, isD = q >> 3, j = (q >> 2) & 1, hd = q & 3;
        const float* att = isD ? ad1 : as1;
        float acc = 0.f;
        for (int ch = 0; ch < 32; ++ch)
            acc = fmaf(W1[j * 128 + hd * 32 + ch], att[hd * 32 + ch], acc);
        AD[isD * 8 + j * 4 + hd] = acc;   // A0|A1|D0|D1, each [4]
    }
}

// ---- pass A: fused degree count + bucket partition (LDS counting sort) ----
__global__ __launch_bounds__(256) void k_part(
        const int* __restrict__ ei, int* __restrict__ deg,
        u32* __restrict__ bcur, u32* __restrict__ stg,
        u32* __restrict__ stg2, u32* __restrict__ ovf) {
    __shared__ u32 lcnt[256], sc[256], lbase[256], gbase[256];
    __shared__ u32 lpair[EPW];
    __shared__ u8  lbkt[EPW];
    int t = threadIdx.x;
    int e0 = blockIdx.x * EPW;
    lcnt[t] = 0;
    __syncthreads();

    u32 pr[16]; u16 rk[16]; u8 bk[16]; bool vd_[16];
#pragma unroll
    for (int j = 0; j < 16; ++j) {
        int e = e0 + j * 256 + t;
        vd_[j] = (e < ET);
        if (vd_[j]) {
            int s, d;
            if (e < NE) { s = ei[e]; d = ei[NE + e]; } else { s = d = e - NE; }
            atomicAdd(deg + d, 1);
            pr[j] = ((u32)d << 16) | (u32)s;
            int b = d >> 8;
            bk[j] = (u8)b;
            rk[j] = (u16)atomicAdd(&lcnt[b], 1u);
        }
    }
    __syncthreads();
    u32 v = lcnt[t];
    sc[t] = v;
    __syncthreads();
#pragma unroll
    for (int st = 1; st < 256; st <<= 1) {
        u32 u = (t >= st) ? sc[t - st] : 0;
        __syncthreads();
        sc[t] += u;
        __syncthreads();
    }
    lbase[t] = sc[t] - v;
    gbase[t] = atomicAdd(&bcur[t], v);
    __syncthreads();
#pragma unroll
    for (int j = 0; j < 16; ++j) if (vd_[j]) {
        u32 idx = lbase[bk[j]] + rk[j];
        lpair[idx] = pr[j];
        lbkt[idx]  = bk[j];
    }
    __syncthreads();
    int nloc = lbase[255] + lcnt[255];
    for (int i = t; i < nloc; i += 256) {
        u32 b = lbkt[i];
        u32 g = gbase[b] + (i - lbase[b]);
        u32 p = lpair[i];
        if (g < BCAP) stg[(size_t)b * BCAP + g] = p;
        else { u32 o = atomicAdd(ovf, 1u); if (o < 4096) stg2[o] = p; }
    }
}

// ---- bucket-base scan: exclusive scan of bcur[0..NB) -> bbase; off[NN]=ET ----
__global__ __launch_bounds__(256) void k_scanb(const u32* __restrict__ bcur,
                                               u32* __restrict__ bbase,
                                               int* __restrict__ off) {
    __shared__ u32 sh[256];
    int t = threadIdx.x;
    u32 v = (t < NB) ? bcur[t] : 0;
    sh[t] = v;
    __syncthreads();
#pragma unroll
    for (int s = 1; s < 256; s <<= 1) {
        u32 u = (t >= s) ? sh[t - s] : 0;
        __syncthreads();
        sh[t] += u;
        __syncthreads();
    }
    if (t < NB) bbase[t] = sh[t] - v;
    if (t == 0) off[NN] = ET;
}

// ---- pass B: one block per bucket; in-block deg scan -> off + LDS cursors;
//      coalesced csr write. Replaces scan_a/scan_c + old k_place. ----
__global__ __launch_bounds__(256) void k_place(
        const int* __restrict__ deg, const u32* __restrict__ bbase,
        const u32* __restrict__ bcur, const u32* __restrict__ stg,
        const u32* __restrict__ stg2, const u32* __restrict__ ovf,
        int* __restrict__ off, u16* __restrict__ csr16) {
    __shared__ u32 sc[256];
    __shared__ u32 lcur[256];
    __shared__ u16 lcsr[BCAP];
    int b = blockIdx.x, t = threadIdx.x;
    int n0 = b << 8;
    int n = n0 + t;
    u32 v = (n < NN) ? (u32)deg[n] : 0;
    sc[t] = v;
    __syncthreads();
#pragma unroll
    for (int s = 1; s < 256; s <<= 1) {
        u32 u = (t >= s) ? sc[t - s] : 0;
        __syncthreads();
        sc[t] += u;
        __syncthreads();
    }
    u32 lexcl = sc[t] - v;
    int S0 = (int)bbase[b];
    if (n < NN) off[n] = S0 + (int)lexcl;
    lcur[t] = lexcl;
    __syncthreads();

    u32 cnt = bcur[b];                    // total edges in this bucket == span
    u32 cmain = min(cnt, (u32)BCAP);
    bool direct = (cnt > BCAP);           // pathological only
    for (u32 i = t; i < cmain; i += 256) {
        u32 p = stg[(size_t)b * BCAP + i];
        u32 nrel = (p >> 16) & 255u;
        u32 r = atomicAdd(&lcur[nrel], 1u);
        if (direct) csr16[S0 + r] = (u16)(p & 0xFFFFu);
        else        lcsr[r] = (u16)(p & 0xFFFFu);
    }
    if (cnt > cmain) {                    // staged overflow (≈never)
        u32 no = min(*ovf, 4096u);
        for (u32 i = t; i < no; i += 256) {
            u32 p = stg2[i];
            if ((p >> 24) == (u32)b) {
                u32 nrel = (p >> 16) & 255u;
                u32 r = atomicAdd(&lcur[nrel], 1u);
                if (direct) csr16[S0 + r] = (u16)(p & 0xFFFFu);
                else        lcsr[r] = (u16)(p & 0xFFFFu);
            }
        }
    }
    __syncthreads();
    if (!direct)
        for (u32 i = t; i < cnt; i += 256) csr16[S0 + i] = lcsr[i];
}

// ---- layer1 aggregate (rank-2) + fused bias/relu + layer-2 attention dots.
//      One wave per node; 16-lane group per head. SINGLE gather pass:
//      x pairs cached in registers (full unroll, static indexing). ----
__global__ __launch_bounds__(128) void k_agg1x(
        const int* __restrict__ off, const u16* __restrict__ csr,
        const float* __restrict__ x, const float* __restrict__ AD,
        const float* __restrict__ W1, const float* __restrict__ b1,
        const float* __restrict__ vs, const float* __restrict__ vd,
        float* __restrict__ x2, float* __restrict__ asrc2,
        float* __restrict__ adst2) {
    int t = threadIdx.x;
    int wv = t >> 6, l = t & 63;
    int n = blockIdx.x * 2 + wv;
    if (n >= NN) return;
    int hd = l >> 4, li = l & 15;
    int e0 = off[n], deg = off[n + 1] - e0;
    float2 xd = *(const float2*)(x + 2 * n);
    float A0 = AD[hd], A1 = AD[4 + hd], D0 = AD[8 + hd], D1 = AD[12 + hd];
    float adn = fmaf(D0, xd.x, D1 * xd.y);

    float den = 0.f, S0 = 0.f, S1 = 0.f;
    if (deg <= 16 * RC) {
        float xx[RC], xy[RC], al[RC];
#pragma unroll
        for (int i = 0; i < RC; ++i) {
            int e = li + i * 16;
            if (e < deg) {
                int s = csr[e0 + e];
                float2 xv = *(const float2*)(x + 2 * s);
                xx[i] = xv.x; xy[i] = xv.y;
                al[i] = lrelu(fmaf(A0, xv.x, A1 * xv.y) + adn);
            } else {
                xx[i] = 0.f; xy[i] = 0.f; al[i] = -1e30f;
            }
        }
        float mymax = -1e30f;
#pragma unroll
        for (int i = 0; i < RC; ++i) mymax = fmaxf(mymax, al[i]);
#pragma unroll
        for (int m = 8; m >= 1; m >>= 1) mymax = fmaxf(mymax, __shfl_xor(mymax, m));
#pragma unroll
        for (int i = 0; i < RC; ++i) {
            float ex = __expf(al[i] - mymax);
            den += ex;
            S0 = fmaf(ex, xx[i], S0);
            S1 = fmaf(ex, xy[i], S1);
        }
    } else {
        // streaming fallback (degree overflow; correctness guarantee)
        float mymax = -1e30f;
        for (int e = li; e < deg; e += 16) {
            int s = csr[e0 + e];
            float2 xv = *(const float2*)(x + 2 * s);
            mymax = fmaxf(mymax, lrelu(fmaf(A0, xv.x, A1 * xv.y) + adn));
        }
#pragma unroll
        for (int m = 8; m >= 1; m >>= 1) mymax = fmaxf(mymax, __shfl_xor(mymax, m));
        for (int e = li; e < deg; e += 16) {
            int s = csr[e0 + e];
            float2 xv = *(const float2*)(x + 2 * s);
            float ex = __expf(lrelu(fmaf(A0, xv.x, A1 * xv.y) + adn) - mymax);
            den += ex;
            S0 = fmaf(ex, xv.x, S0);
            S1 = fmaf(ex, xv.y, S1);
        }
    }
#pragma unroll
    for (int m = 8; m >= 1; m >>= 1) {
        den += __shfl_xor(den, m);
        S0  += __shfl_xor(S0, m);
        S1  += __shfl_xor(S1, m);
    }
    float inv = 1.f / (den + 1e-16f);

    int c0 = 2 * l;
    float o0 = (S0 * W1[c0]     + S1 * W1[128 + c0])     * inv;
    float o1 = (S0 * W1[c0 + 1] + S1 * W1[128 + c0 + 1]) * inv;
    float v0 = fmaxf(o0 + b1[c0], 0.f);
    float v1 = fmaxf(o1 + b1[c0 + 1], 0.f);
    *(float2*)(x2 + (size_t)n * 128 + c0) = make_float2(v0, v1);

    float ps = fmaf(v0, vs[c0], v1 * vs[c0 + 1]);
    float pd = fmaf(v0, vd[c0], v1 * vd[c0 + 1]);
#pragma unroll
    for (int m = 32; m >= 1; m >>= 1) {
        ps += __shfl_xor(ps, m);
        pd += __shfl_xor(pd, m);
    }
    if (l == 0) { asrc2[n] = ps; adst2[n] = pd; }
}

// ---- layer2 softmax weights: SINGLE gather pass with register cache;
//      per-edge coef -> atomicAdd(w[src]). 16 lanes/node, 8 nodes/block. ----
__global__ __launch_bounds__(128) void k_sm2(
        const int* __restrict__ off, const u16* __restrict__ csr,
        const float* __restrict__ asrc2, const float* __restrict__ adst2,
        float* __restrict__ w) {
    int t = threadIdx.x;
    int g = t >> 4, li = t & 15;
    int n = blockIdx.x * 8 + g;
    if (n >= NN) return;
    int e0 = off[n], deg = off[n + 1] - e0;
    float adn = adst2[n];

    if (deg <= 16 * RC) {
        float al[RC]; int sr[RC];
#pragma unroll
        for (int i = 0; i < RC; ++i) {
            int e = li + i * 16;
            if (e < deg) {
                int s = csr[e0 + e];
                sr[i] = s;
                al[i] = lrelu(asrc2[s] + adn);
            } else {
                sr[i] = 0; al[i] = -1e30f;
            }
        }
        float mymax = -1e30f;
#pragma unroll
        for (int i = 0; i < RC; ++i) mymax = fmaxf(mymax, al[i]);
#pragma unroll
        for (int m = 8; m >= 1; m >>= 1) mymax = fmaxf(mymax, __shfl_xor(mymax, m));
        float den = 0.f;
#pragma unroll
        for (int i = 0; i < RC; ++i) {
            float ex = __expf(al[i] - mymax);
            al[i] = ex;
            den += ex;
        }
#pragma unroll
        for (int m = 8; m >= 1; m >>= 1) den += __shfl_xor(den, m);
        float inv = 1.f / (den + 1e-16f);
#pragma unroll
        for (int i = 0; i < RC; ++i)
            if (li + i * 16 < deg) atomicAdd(w + sr[i], al[i] * inv);
    } else {
        // streaming fallback
        float mymax = -1e30f;
        for (int e = li; e < deg; e += 16)
            mymax = fmaxf(mymax, lrelu(asrc2[csr[e0 + e]] + adn));
#pragma unroll
        for (int m = 8; m >= 1; m >>= 1) mymax = fmaxf(mymax, __shfl_xor(mymax, m));
        float den = 0.f;
        for (int e = li; e < deg; e += 16)
            den += __expf(lrelu(asrc2[csr[e0 + e]] + adn) - mymax);
#pragma unroll
        for (int m = 8; m >= 1; m >>= 1) den += __shfl_xor(den, m);
        float inv = 1.f / (den + 1e-16f);
        for (int e = li; e < deg; e += 16) {
            int s = csr[e0 + e];
            float coef = __expf(lrelu(asrc2[s] + adn) - mymax) * inv;
            atomicAdd(w + s, coef);
        }
    }
}

// ---- weighted column sum: z = sum_n w[n] * x2[n] ----
__global__ __launch_bounds__(256) void k_wsum(const float* __restrict__ w,
                                              const float* __restrict__ x2,
                                              float* __restrict__ z) {
    __shared__ float red[256];
    int t = threadIdx.x, c = t & 127, rp = t >> 7;
    float acc = 0.f;
    for (int n = blockIdx.x * 2 + rp; n < NN; n += 2048)
        acc = fmaf(w[n], x2[(size_t)n * 128 + c], acc);
    red[t] = acc;
    __syncthreads();
    if (t < 128) atomicAdd(z + t, red[t] + red[t + 128]);
}

// ---- final: d_out = b2 + (z @ W2) / N  (128x128 GEMV, one block) ----
__global__ __launch_bounds__(128) void k_out(const float* __restrict__ z,
                                             const float* __restrict__ W2,
                                             const float* __restrict__ b2,
                                             float* __restrict__ out) {
    int c = threadIdx.x;
    float acc = 0.f;
    for (int k = 0; k < 128; ++k)
        acc = fmaf(z[k], W2[k * 128 + c], acc);
    out[c] = b2[c] + acc * (1.0f / NN);
}

extern "C" void kernel_launch(void* const* d_in, const int* in_sizes, int n_in,
                              void* d_out, int out_size, void* d_ws, size_t ws_size,
                              hipStream_t stream) {
    const float* x   = (const float*)d_in[0];
    const int*   ei  = (const int*)d_in[1];
    const float* W1  = (const float*)d_in[2];
    const float* as1 = (const float*)d_in[3];
    const float* ad1 = (const float*)d_in[4];
    const float* b1  = (const float*)d_in[5];
    const float* W2  = (const float*)d_in[6];
    const float* as2 = (const float*)d_in[7];
    const float* ad2 = (const float*)d_in[8];
    const float* b2  = (const float*)d_in[9];
    float* out = (float*)d_out;

    char* ws     = (char*)d_ws;
    float* x2    = (float*)ws;                           // NN*128 f32
    u32*  stg    = (u32*)x2;                             // ALIAS: dead before x2 written
    float* w     = x2 + (size_t)NN * 128;                // NN
    float* asrc2 = w + NN;                               // NN
    float* adst2 = asrc2 + NN;                           // NN
    int* deg     = (int*)(adst2 + NN);                   // NN
    int* off     = deg + NN;                             // NN+1
    u32* bcur    = (u32*)(off + NN + 1);                 // 256
    u32* bbase   = bcur + 256;                           // 256
    u32* ovf     = bbase + 256;                          // 4
    u32* stg2    = ovf + 4;                              // 4096
    u16* csr16   = (u16*)(stg2 + 4096);                  // ET u16
    float* AD    = (float*)(csr16 + ET);                 // 16
    float* vs    = AD + 16;                              // 128
    float* vd    = vs + 128;                             // 128
    float* z     = vd + 128;                             // 128

    // init + precompute attention projections
    k_init<<<(NN + 255) / 256, 256, 0, stream>>>(deg, w, bcur, ovf, z,
                                                 W1, as1, ad1, W2, as2, ad2,
                                                 AD, vs, vd);
    // CSR build: partition, bucket-base scan, place (writes off + csr)
    k_part<<<NWGP, 256, 0, stream>>>(ei, deg, bcur, stg, stg2, ovf);
    k_scanb<<<1, 256, 0, stream>>>(bcur, bbase, off);
    k_place<<<NB, 256, 0, stream>>>(deg, bbase, bcur, stg, stg2, ovf, off, csr16);

    // layer 1 (rank-2) + fused layer-2 dots
    k_agg1x<<<(NN + 1) / 2, 128, 0, stream>>>(off, csr16, x, AD, W1, b1,
                                              vs, vd, x2, asrc2, adst2);
    // layer 2 softmax weights, weighted sum, output GEMV
    k_sm2<<<(NN + 7) / 8, 128, 0, stream>>>(off, csr16, asrc2, adst2, w);
    k_wsum<<<1024, 256, 0, stream>>>(w, x2, z);
    k_out<<<1, 128, 0, stream>>>(z, W2, b2, out);
}

// Round 16
// 144.432 us; speedup vs baseline: 2.4667x; 1.2676x over previous
//
#include <hip/hip_runtime.h>

#define NN 50000
#define NE 800000
#define ET (NE + NN)   // 850000 edges incl. self-loops
#define EPW 4096       // edges per k_part workgroup
#define NWGP ((ET + EPW - 1) / EPW)         // 208
#define NB 196         // buckets = id>>8 (aligned with 256-node tiles)
#define BCAP 6144      // staging capacity per bucket (mean 4337, sd ~66)
#define RC 8           // register-cache slots per lane (fast path deg <= 128)

typedef unsigned short u16;
typedef unsigned int u32;
typedef unsigned char u8;

__device__ __forceinline__ float lrelu(float a) { return a > 0.f ? a : 0.2f * a; }

// ---- init: zero bcur/bcur2/ovf/ovf2/z; precompute AD (2x4 attn dots of W1)
//      and vs,vd (W2 @ as2 / ad2) ----
__global__ void k_init(u32* __restrict__ bcur, u32* __restrict__ bcur2,
                       u32* __restrict__ ovf, u32* __restrict__ ovf2,
                       float* __restrict__ z,
                       const float* __restrict__ W1, const float* __restrict__ as1,
                       const float* __restrict__ ad1, const float* __restrict__ W2,
                       const float* __restrict__ as2, const float* __restrict__ ad2,
                       float* __restrict__ AD, float* __restrict__ vs,
                       float* __restrict__ vd) {
    int i = blockIdx.x * blockDim.x + threadIdx.x;
    if (i < 256) { bcur[i] = 0; bcur2[i] = 0; }
    if (i == 0)  { *ovf = 0; *ovf2 = 0; }
    if (i < 128) {
        z[i] = 0.f;
        float a = 0.f, d = 0.f;
        for (int c = 0; c < 128; ++c) {
            float wv = W2[i * 128 + c];
            a = fmaf(wv, as2[c], a);
            d = fmaf(wv, ad2[c], d);
        }
        vs[i] = a; vd[i] = d;
    }
    if (i >= 128 && i < 144) {
        int q = i - 128, isD = q >> 3, j = (q >> 2) & 1, hd = q & 3;
        const float* att = isD ? ad1 : as1;
        float acc = 0.f;
        for (int ch = 0; ch < 32; ++ch)
            acc = fmaf(W1[j * 128 + hd * 32 + ch], att[hd * 32 + ch], acc);
        AD[isD * 8 + j * 4 + hd] = acc;   // A0|A1|D0|D1, each [4]
    }
}

// ---- pass A: dual LDS counting sort — by dst into stg, by src into stg_s.
//      Edges loaded once; pairs kept in registers between the two sorts.
//      NO per-node global atomics (deg derived in k_place). ----
__global__ __launch_bounds__(256) void k_part(
        const int* __restrict__ ei,
        u32* __restrict__ bcur, u32* __restrict__ bcur2,
        u32* __restrict__ stg, u32* __restrict__ stg_s,
        u32* __restrict__ stg2, u32* __restrict__ stg2s,
        u32* __restrict__ ovf, u32* __restrict__ ovf2) {
    __shared__ u32 lcnt[256], sc[256], lbase[256], gbase[256];
    __shared__ u32 lpair[EPW];
    __shared__ u8  lbkt[EPW];
    int t = threadIdx.x;
    int e0 = blockIdx.x * EPW;

    u32 pr[16]; bool vd_[16]; u16 rk[16]; u8 bk[16];
#pragma unroll
    for (int j = 0; j < 16; ++j) {
        int e = e0 + j * 256 + t;
        vd_[j] = (e < ET);
        if (vd_[j]) {
            int s, d;
            if (e < NE) { s = ei[e]; d = ei[NE + e]; } else { s = d = e - NE; }
            pr[j] = ((u32)d << 16) | (u32)s;
        }
    }
    // ---- sort 1: key = dst ----
    lcnt[t] = 0;
    __syncthreads();
#pragma unroll
    for (int j = 0; j < 16; ++j) if (vd_[j]) {
        int b = pr[j] >> 24;                   // d>>8
        bk[j] = (u8)b;
        rk[j] = (u16)atomicAdd(&lcnt[b], 1u);
    }
    __syncthreads();
    u32 v = lcnt[t];
    sc[t] = v;
    __syncthreads();
#pragma unroll
    for (int st = 1; st < 256; st <<= 1) {
        u32 u = (t >= st) ? sc[t - st] : 0;
        __syncthreads();
        sc[t] += u;
        __syncthreads();
    }
    lbase[t] = sc[t] - v;
    gbase[t] = atomicAdd(&bcur[t], v);
    __syncthreads();
#pragma unroll
    for (int j = 0; j < 16; ++j) if (vd_[j]) {
        u32 idx = lbase[bk[j]] + rk[j];
        lpair[idx] = pr[j];
        lbkt[idx]  = bk[j];
    }
    __syncthreads();
    int nloc = lbase[255] + lcnt[255];
    for (int i = t; i < nloc; i += 256) {
        u32 b = lbkt[i];
        u32 g = gbase[b] + (i - lbase[b]);
        u32 p = lpair[i];
        if (g < BCAP) stg[(size_t)b * BCAP + g] = p;
        else { u32 o = atomicAdd(ovf, 1u); if (o < 4096) stg2[o] = p; }
    }
    __syncthreads();
    // ---- sort 2: key = src; pair stored as (s<<16|d) via half-swap ----
    lcnt[t] = 0;
    __syncthreads();
#pragma unroll
    for (int j = 0; j < 16; ++j) if (vd_[j]) {
        int b = (pr[j] & 0xFFFFu) >> 8;        // s>>8
        bk[j] = (u8)b;
        rk[j] = (u16)atomicAdd(&lcnt[b], 1u);
    }
    __syncthreads();
    v = lcnt[t];
    sc[t] = v;
    __syncthreads();
#pragma unroll
    for (int st = 1; st < 256; st <<= 1) {
        u32 u = (t >= st) ? sc[t - st] : 0;
        __syncthreads();
        sc[t] += u;
        __syncthreads();
    }
    lbase[t] = sc[t] - v;
    gbase[t] = atomicAdd(&bcur2[t], v);
    __syncthreads();
#pragma unroll
    for (int j = 0; j < 16; ++j) if (vd_[j]) {
        u32 p2 = (pr[j] << 16) | (pr[j] >> 16);
        u32 idx = lbase[bk[j]] + rk[j];
        lpair[idx] = p2;
        lbkt[idx]  = bk[j];
    }
    __syncthreads();
    nloc = lbase[255] + lcnt[255];
    for (int i = t; i < nloc; i += 256) {
        u32 b = lbkt[i];
        u32 g = gbase[b] + (i - lbase[b]);
        u32 p = lpair[i];
        if (g < BCAP) stg_s[(size_t)b * BCAP + g] = p;
        else { u32 o = atomicAdd(ovf2, 1u); if (o < 4096) stg2s[o] = p; }
    }
}

// ---- bucket-base scans: bcur->bbase, bcur2->bbase2; off tails ----
__global__ __launch_bounds__(256) void k_scanb(
        const u32* __restrict__ bcur, u32* __restrict__ bbase,
        const u32* __restrict__ bcur2, u32* __restrict__ bbase2,
        int* __restrict__ off, int* __restrict__ off_s) {
    __shared__ u32 sh[256];
    int t = threadIdx.x;
    u32 v = (t < NB) ? bcur[t] : 0;
    sh[t] = v;
    __syncthreads();
#pragma unroll
    for (int s = 1; s < 256; s <<= 1) {
        u32 u = (t >= s) ? sh[t - s] : 0;
        __syncthreads();
        sh[t] += u;
        __syncthreads();
    }
    if (t < NB) bbase[t] = sh[t] - v;
    __syncthreads();
    u32 v2 = (t < NB) ? bcur2[t] : 0;
    sh[t] = v2;
    __syncthreads();
#pragma unroll
    for (int s = 1; s < 256; s <<= 1) {
        u32 u = (t >= s) ? sh[t - s] : 0;
        __syncthreads();
        sh[t] += u;
        __syncthreads();
    }
    if (t < NB) bbase2[t] = sh[t] - v2;
    if (t == 0) { off[NN] = ET; off_s[NN] = ET; }
}

// ---- pass B (unified CSR/CSC): one block per bucket. LDS histogram of the
//      bucket's pairs -> per-node offsets (off) + cursors; coalesced write. ----
__global__ __launch_bounds__(256) void k_place(
        const u32* __restrict__ bbase, const u32* __restrict__ bcur,
        const u32* __restrict__ stg, const u32* __restrict__ stg2,
        const u32* __restrict__ ovf,
        int* __restrict__ off, u16* __restrict__ out16) {
    __shared__ u32 hist[256], sc[256], lcur[256];
    __shared__ u16 lcsr[BCAP];
    int b = blockIdx.x, t = threadIdx.x;
    int n0 = b << 8;
    int S0 = (int)bbase[b];
    u32 cnt = bcur[b];
    hist[t] = 0;
    __syncthreads();
    u32 cmain = min(cnt, (u32)BCAP);
    for (u32 i = t; i < cmain; i += 256)
        atomicAdd(&hist[(stg[(size_t)b * BCAP + i] >> 16) & 255u], 1u);
    if (cnt > cmain) {
        u32 no = min(*ovf, 4096u);
        for (u32 i = t; i < no; i += 256) {
            u32 p = stg2[i];
            if ((p >> 24) == (u32)b) atomicAdd(&hist[(p >> 16) & 255u], 1u);
        }
    }
    __syncthreads();
    u32 v = hist[t];
    sc[t] = v;
    __syncthreads();
#pragma unroll
    for (int s = 1; s < 256; s <<= 1) {
        u32 u = (t >= s) ? sc[t - s] : 0;
        __syncthreads();
        sc[t] += u;
        __syncthreads();
    }
    u32 lexcl = sc[t] - v;
    int n = n0 + t;
    if (n < NN) off[n] = S0 + (int)lexcl;
    lcur[t] = lexcl;
    __syncthreads();
    bool direct = (cnt > (u32)BCAP);       // pathological only
    for (u32 i = t; i < cmain; i += 256) {
        u32 p = stg[(size_t)b * BCAP + i];
        u32 r = atomicAdd(&lcur[(p >> 16) & 255u], 1u);
        if (direct) out16[S0 + r] = (u16)(p & 0xFFFFu);
        else        lcsr[r] = (u16)(p & 0xFFFFu);
    }
    if (cnt > cmain) {
        u32 no = min(*ovf, 4096u);
        for (u32 i = t; i < no; i += 256) {
            u32 p = stg2[i];
            if ((p >> 24) == (u32)b) {
                u32 r = atomicAdd(&lcur[(p >> 16) & 255u], 1u);
                if (direct) out16[S0 + r] = (u16)(p & 0xFFFFu);
                else        lcsr[r] = (u16)(p & 0xFFFFu);
            }
        }
    }
    __syncthreads();
    if (!direct)
        for (u32 i = t; i < cnt; i += 256) out16[S0 + i] = lcsr[i];
}

// ---- layer1 aggregate (rank-2) + fused bias/relu + layer-2 attention dots ----
__global__ __launch_bounds__(128) void k_agg1x(
        const int* __restrict__ off, const u16* __restrict__ csr,
        const float* __restrict__ x, const float* __restrict__ AD,
        const float* __restrict__ W1, const float* __restrict__ b1,
        const float* __restrict__ vs, const float* __restrict__ vd,
        float* __restrict__ x2, float* __restrict__ asrc2,
        float* __restrict__ adst2) {
    int t = threadIdx.x;
    int wv = t >> 6, l = t & 63;
    int n = blockIdx.x * 2 + wv;
    if (n >= NN) return;
    int hd = l >> 4, li = l & 15;
    int e0 = off[n], deg = off[n + 1] - e0;
    float2 xd = *(const float2*)(x + 2 * n);
    float A0 = AD[hd], A1 = AD[4 + hd], D0 = AD[8 + hd], D1 = AD[12 + hd];
    float adn = fmaf(D0, xd.x, D1 * xd.y);

    float den = 0.f, S0 = 0.f, S1 = 0.f;
    if (deg <= 16 * RC) {
        float xx[RC], xy[RC], al[RC];
#pragma unroll
        for (int i = 0; i < RC; ++i) {
            int e = li + i * 16;
            if (e < deg) {
                int s = csr[e0 + e];
                float2 xv = *(const float2*)(x + 2 * s);
                xx[i] = xv.x; xy[i] = xv.y;
                al[i] = lrelu(fmaf(A0, xv.x, A1 * xv.y) + adn);
            } else {
                xx[i] = 0.f; xy[i] = 0.f; al[i] = -1e30f;
            }
        }
        float mymax = -1e30f;
#pragma unroll
        for (int i = 0; i < RC; ++i) mymax = fmaxf(mymax, al[i]);
#pragma unroll
        for (int m = 8; m >= 1; m >>= 1) mymax = fmaxf(mymax, __shfl_xor(mymax, m));
#pragma unroll
        for (int i = 0; i < RC; ++i) {
            float ex = __expf(al[i] - mymax);
            den += ex;
            S0 = fmaf(ex, xx[i], S0);
            S1 = fmaf(ex, xy[i], S1);
        }
    } else {
        float mymax = -1e30f;
        for (int e = li; e < deg; e += 16) {
            int s = csr[e0 + e];
            float2 xv = *(const float2*)(x + 2 * s);
            mymax = fmaxf(mymax, lrelu(fmaf(A0, xv.x, A1 * xv.y) + adn));
        }
#pragma unroll
        for (int m = 8; m >= 1; m >>= 1) mymax = fmaxf(mymax, __shfl_xor(mymax, m));
        for (int e = li; e < deg; e += 16) {
            int s = csr[e0 + e];
            float2 xv = *(const float2*)(x + 2 * s);
            float ex = __expf(lrelu(fmaf(A0, xv.x, A1 * xv.y) + adn) - mymax);
            den += ex;
            S0 = fmaf(ex, xv.x, S0);
            S1 = fmaf(ex, xv.y, S1);
        }
    }
#pragma unroll
    for (int m = 8; m >= 1; m >>= 1) {
        den += __shfl_xor(den, m);
        S0  += __shfl_xor(S0, m);
        S1  += __shfl_xor(S1, m);
    }
    float inv = 1.f / (den + 1e-16f);

    int c0 = 2 * l;
    float o0 = (S0 * W1[c0]     + S1 * W1[128 + c0])     * inv;
    float o1 = (S0 * W1[c0 + 1] + S1 * W1[128 + c0 + 1]) * inv;
    float v0 = fmaxf(o0 + b1[c0], 0.f);
    float v1 = fmaxf(o1 + b1[c0 + 1], 0.f);
    *(float2*)(x2 + (size_t)n * 128 + c0) = make_float2(v0, v1);

    float ps = fmaf(v0, vs[c0], v1 * vs[c0 + 1]);
    float pd = fmaf(v0, vd[c0], v1 * vd[c0 + 1]);
#pragma unroll
    for (int m = 32; m >= 1; m >>= 1) {
        ps += __shfl_xor(ps, m);
        pd += __shfl_xor(pd, m);
    }
    if (l == 0) { asrc2[n] = ps; adst2[n] = pd; }
}

// ---- layer2 per-dst softmax stats: mxinv[n] = {max, 1/den} (CSR gather) ----
__global__ __launch_bounds__(128) void k_den(
        const int* __restrict__ off, const u16* __restrict__ csr,
        const float* __restrict__ asrc2, const float* __restrict__ adst2,
        float2* __restrict__ mxinv) {
    int t = threadIdx.x;
    int g = t >> 4, li = t & 15;
    int n = blockIdx.x * 8 + g;
    if (n >= NN) return;
    int e0 = off[n], deg = off[n + 1] - e0;
    float adn = adst2[n];
    float mymax = -1e30f, den = 0.f;
    if (deg <= 16 * RC) {
        float al[RC];
#pragma unroll
        for (int i = 0; i < RC; ++i) {
            int e = li + i * 16;
            al[i] = (e < deg) ? lrelu(asrc2[csr[e0 + e]] + adn) : -1e30f;
        }
#pragma unroll
        for (int i = 0; i < RC; ++i) mymax = fmaxf(mymax, al[i]);
#pragma unroll
        for (int m = 8; m >= 1; m >>= 1) mymax = fmaxf(mymax, __shfl_xor(mymax, m));
#pragma unroll
        for (int i = 0; i < RC; ++i) den += __expf(al[i] - mymax);
    } else {
        for (int e = li; e < deg; e += 16)
            mymax = fmaxf(mymax, lrelu(asrc2[csr[e0 + e]] + adn));
#pragma unroll
        for (int m = 8; m >= 1; m >>= 1) mymax = fmaxf(mymax, __shfl_xor(mymax, m));
        for (int e = li; e < deg; e += 16)
            den += __expf(lrelu(asrc2[csr[e0 + e]] + adn) - mymax);
    }
#pragma unroll
    for (int m = 8; m >= 1; m >>= 1) den += __shfl_xor(den, m);
    if (li == 0) mxinv[n] = make_float2(mymax, 1.f / (den + 1e-16f));
}

// ---- layer2 softmax weights via CSC gather: w[s] = sum over out-edges.
//      ZERO atomics: one plain write per node. ----
__global__ __launch_bounds__(128) void k_wgath(
        const int* __restrict__ off_s, const u16* __restrict__ csc,
        const float* __restrict__ asrc2, const float* __restrict__ adst2,
        const float2* __restrict__ mxinv, float* __restrict__ w) {
    int t = threadIdx.x;
    int g = t >> 4, li = t & 15;
    int n = blockIdx.x * 8 + g;
    if (n >= NN) return;
    int e0 = off_s[n], deg = off_s[n + 1] - e0;
    float as = asrc2[n];
    float acc = 0.f;
    if (deg <= 16 * RC) {
#pragma unroll
        for (int i = 0; i < RC; ++i) {
            int e = li + i * 16;
            if (e < deg) {
                int d = csc[e0 + e];
                float2 mi = mxinv[d];
                acc += __expf(lrelu(as + adst2[d]) - mi.x) * mi.y;
            }
        }
    } else {
        for (int e = li; e < deg; e += 16) {
            int d = csc[e0 + e];
            float2 mi = mxinv[d];
            acc += __expf(lrelu(as + adst2[d]) - mi.x) * mi.y;
        }
    }
#pragma unroll
    for (int m = 8; m >= 1; m >>= 1) acc += __shfl_xor(acc, m);
    if (li == 0) w[n] = acc;
}

// ---- weighted column sum: z = sum_n w[n] * x2[n] ----
__global__ __launch_bounds__(256) void k_wsum(const float* __restrict__ w,
                                              const float* __restrict__ x2,
                                              float* __restrict__ z) {
    __shared__ float red[256];
    int t = threadIdx.x, c = t & 127, rp = t >> 7;
    float acc = 0.f;
    for (int n = blockIdx.x * 2 + rp; n < NN; n += 2048)
        acc = fmaf(w[n], x2[(size_t)n * 128 + c], acc);
    red[t] = acc;
    __syncthreads();
    if (t < 128) atomicAdd(z + t, red[t] + red[t + 128]);
}

// ---- final: d_out = b2 + (z @ W2) / N ----
__global__ __launch_bounds__(128) void k_out(const float* __restrict__ z,
                                             const float* __restrict__ W2,
                                             const float* __restrict__ b2,
                                             float* __restrict__ out) {
    int c = threadIdx.x;
    float acc = 0.f;
    for (int k = 0; k < 128; ++k)
        acc = fmaf(z[k], W2[k * 128 + c], acc);
    out[c] = b2[c] + acc * (1.0f / NN);
}

extern "C" void kernel_launch(void* const* d_in, const int* in_sizes, int n_in,
                              void* d_out, int out_size, void* d_ws, size_t ws_size,
                              hipStream_t stream) {
    const float* x   = (const float*)d_in[0];
    const int*   ei  = (const int*)d_in[1];
    const float* W1  = (const float*)d_in[2];
    const float* as1 = (const float*)d_in[3];
    const float* ad1 = (const float*)d_in[4];
    const float* b1  = (const float*)d_in[5];
    const float* W2  = (const float*)d_in[6];
    const float* as2 = (const float*)d_in[7];
    const float* ad2 = (const float*)d_in[8];
    const float* b2  = (const float*)d_in[9];
    float* out = (float*)d_out;

    char* ws     = (char*)d_ws;
    float* x2    = (float*)ws;                           // NN*128 f32
    u32*  stg    = (u32*)x2;                             // ALIAS (dead pre-agg1x)
    u32*  stg_s  = stg + (size_t)NB * BCAP;              // ALIAS (dead pre-agg1x)
    float* w     = x2 + (size_t)NN * 128;                // NN
    float* asrc2 = w + NN;                               // NN
    float* adst2 = asrc2 + NN;                           // NN
    float2* mxinv = (float2*)(adst2 + NN);               // NN float2
    int* off     = (int*)(mxinv + NN);                   // NN+1
    int* off_s   = off + NN + 1;                         // NN+1
    u32* bcur    = (u32*)(off_s + NN + 1);               // 256
    u32* bcur2   = bcur + 256;                           // 256
    u32* bbase   = bcur2 + 256;                          // 256
    u32* bbase2  = bbase + 256;                          // 256
    u32* ovf     = bbase2 + 256;                         // 4
    u32* ovf2    = ovf + 4;                              // 4
    u32* stg2    = ovf2 + 4;                             // 4096
    u32* stg2s   = stg2 + 4096;                          // 4096
    u16* csr16   = (u16*)(stg2s + 4096);                 // ET u16
    u16* csc16   = csr16 + ET;                           // ET u16
    float* AD    = (float*)(csc16 + ET);                 // 16
    float* vs    = AD + 16;                              // 128
    float* vd    = vs + 128;                             // 128
    float* z     = vd + 128;                             // 128

    // init + precompute attention projections
    k_init<<<(NN + 255) / 256, 256, 0, stream>>>(bcur, bcur2, ovf, ovf2, z,
                                                 W1, as1, ad1, W2, as2, ad2,
                                                 AD, vs, vd);
    // dual-sort partition; bucket-base scans; place CSR + CSC
    k_part<<<NWGP, 256, 0, stream>>>(ei, bcur, bcur2, stg, stg_s,
                                     stg2, stg2s, ovf, ovf2);
    k_scanb<<<1, 256, 0, stream>>>(bcur, bbase, bcur2, bbase2, off, off_s);
    k_place<<<NB, 256, 0, stream>>>(bbase, bcur, stg, stg2, ovf, off, csr16);
    k_place<<<NB, 256, 0, stream>>>(bbase2, bcur2, stg_s, stg2s, ovf2, off_s, csc16);

    // layer 1 (rank-2) + fused layer-2 dots
    k_agg1x<<<(NN + 1) / 2, 128, 0, stream>>>(off, csr16, x, AD, W1, b1,
                                              vs, vd, x2, asrc2, adst2);
    // layer 2: per-dst stats (CSR), per-src weights (CSC, no atomics)
    k_den<<<(NN + 7) / 8, 128, 0, stream>>>(off, csr16, asrc2, adst2, mxinv);
    k_wgath<<<(NN + 7) / 8, 128, 0, stream>>>(off_s, csc16, asrc2, adst2, mxinv, w);
    // weighted sum + output GEMV
    k_wsum<<<1024, 256, 0, stream>>>(w, x2, z);
    k_out<<<1, 128, 0, stream>>>(z, W2, b2, out);
}